// Round 3
// baseline (2354.686 us; speedup 1.0000x reference)
//
#include <hip/hip_runtime.h>
#include <stdint.h>

typedef __attribute__((ext_vector_type(4))) float f32x4;
typedef __attribute__((ext_vector_type(8))) short bf16x8;
typedef __attribute__((ext_vector_type(4))) short bf16x4v;
typedef __attribute__((ext_vector_type(4))) unsigned int u32x4;

#define NBATCH 8
#define LQS    1024
#define LKS    4096
#define DDIM   1024
#define QKSCALE 0.03125f
#define NEGINF -1000000000.0f

__device__ __forceinline__ float bf2f(short s) {
    unsigned u = ((unsigned)(unsigned short)s) << 16;
    return __builtin_bit_cast(float, u);
}
__device__ __forceinline__ short f2bf(float x) {  // round-to-nearest-even
    unsigned u = __builtin_bit_cast(unsigned, x);
    unsigned r = (u + 0x7fffu + ((u >> 16) & 1u)) >> 16;
    return (short)r;
}

// ---- runtime dtype detection (deterministic on fixed inputs) ----
// flags[0]: mask is int32 (else uint8 bool)
// flags[1]: float inputs are bf16 (else fp32)
__global__ void detect_kernel(const unsigned char* __restrict__ mb,
                              const unsigned char* __restrict__ vb,
                              int* __restrict__ flags) {
    if (threadIdx.x != 0 || blockIdx.x != 0) return;
    int is_i32 = 1;
    for (int i = 0; i < 256; ++i) {
        if ((i & 3) != 0 && mb[i] != 0) { is_i32 = 0; break; }
    }
    flags[0] = is_i32;
    // byte at 4i+1: bf16 stream -> always sign/exp byte of element 2i
    // (exp>>1 in [40,64] for N(0,1)); fp32 stream -> mantissa byte (uniform).
    int inset = 0;
    for (int i = 0; i < 256; ++i) {
        unsigned e = vb[4 * i + 1] & 0x7fu;
        inset += (e >= 40u && e <= 64u) ? 1 : 0;
    }
    flags[1] = (inset >= 200) ? 1 : 0;
}

// 8 contiguous logical elements -> bf16x8. fp32 path: v_perm high-half pack (trunc).
template <int ISBF>
__device__ __forceinline__ bf16x8 load8(const void* base, size_t elem) {
    if constexpr (ISBF) {
        return *(const bf16x8*)((const short*)base + elem);
    } else {
        const u32x4* u = (const u32x4*)((const float*)base + elem);
        const u32x4 a = u[0], b = u[1];
        union { unsigned w[4]; bf16x8 v; } c;
        c.w[0] = __builtin_amdgcn_perm(a[1], a[0], 0x07060302u);
        c.w[1] = __builtin_amdgcn_perm(a[3], a[2], 0x07060302u);
        c.w[2] = __builtin_amdgcn_perm(b[1], b[0], 0x07060302u);
        c.w[3] = __builtin_amdgcn_perm(b[3], b[2], 0x07060302u);
        return c.v;
    }
}

// RNE variant (used for Q, loaded once per block)
template <int ISBF>
__device__ __forceinline__ bf16x8 load8rne(const void* base, size_t elem) {
    if constexpr (ISBF) {
        return *(const bf16x8*)((const short*)base + elem);
    } else {
        const float* f = (const float*)base + elem;
        const f32x4 a = *(const f32x4*)f, b = *(const f32x4*)(f + 4);
        bf16x8 r;
        r[0] = f2bf(a[0]); r[1] = f2bf(a[1]); r[2] = f2bf(a[2]); r[3] = f2bf(a[3]);
        r[4] = f2bf(b[0]); r[5] = f2bf(b[1]); r[6] = f2bf(b[2]); r[7] = f2bf(b[3]);
        return r;
    }
}

// ---- flash attention body: 512 blocks = 8 b x 64 qtiles(16 rows); 4 waves split D
template <int ISBF>
__device__ __forceinline__ void attn_body(
    const void* __restrict__ qm, const void* __restrict__ km,
    const void* __restrict__ vm, const void* __restrict__ mask,
    const int mflag, short* __restrict__ attedT,
    short* __restrict__ Vt, float* __restrict__ Spart) {

    const int tid  = threadIdx.x;
    const int w    = tid >> 6;
    const int lane = tid & 63;
    const int lo   = lane & 15;
    const int g    = lane >> 4;
    const int b    = blockIdx.x >> 6;
    const int qt   = blockIdx.x & 63;

    const int qrow = qt * 16 + lo;

    // Q fragments (B-operand): lane holds Q[qrow][w*256 + f*32 + g*8 + j]
    bf16x8 qfrag[8];
    {
        const size_t qb = ((size_t)b * LQS + qrow) * DDIM + w * 256 + g * 8;
#pragma unroll
        for (int f = 0; f < 8; ++f) qfrag[f] = load8rne<ISBF>(qm, qb + f * 32);
    }

    // K fragment base (A-operand): row kk0+lo, cols w*256 + f*32 + g*8
    const size_t kb0 = ((size_t)b * LKS + lo) * DDIM + w * 256 + g * 8;
    bf16x8 kreg[8];
#pragma unroll
    for (int f = 0; f < 8; ++f) kreg[f] = load8<ISBF>(km, kb0 + f * 32);

    const size_t moff = ((size_t)b * LQS + qrow) * LKS + g * 4;
    const size_t vb0  = (size_t)b * LKS * DDIM;

    f32x4 acc[16];
#pragma unroll
    for (int ch = 0; ch < 16; ++ch) acc[ch] = (f32x4){0.f, 0.f, 0.f, 0.f};
    float m_run = -INFINITY, l_run = 0.f;

    for (int t = 0; t < 256; ++t) {
        const int kk0 = t * 16;

        // stage V tile [16][1028]
        {
            const int r0 = tid >> 7;
            const int c  = (tid & 127) * 8;
#pragma unroll
            for (int p = 0; p < 8; ++p) {
                const int r = p * 2 + r0;
                const bf16x8 vv = load8<ISBF>(vm, vb0 + (size_t)(kk0 + r) * DDIM + c);
                *(bf16x4v*)&Vt[r * 1028 + c]     = __builtin_shufflevector(vv, vv, 0, 1, 2, 3);
                *(bf16x4v*)&Vt[r * 1028 + c + 4] = __builtin_shufflevector(vv, vv, 4, 5, 6, 7);
            }
        }

        // QK^T partial (swapped: mfma(K,Q) -> S^T): lane gets (q=lo col, kk=g*4+r row)
        f32x4 sp = {0.f, 0.f, 0.f, 0.f};
#pragma unroll
        for (int f = 0; f < 8; ++f)
            sp = __builtin_amdgcn_mfma_f32_16x16x32_bf16(kreg[f], qfrag[f], sp, 0, 0, 0);

        // prefetch next K tile
        if (t < 255) {
            const size_t kn = kb0 + (size_t)(kk0 + 16) * DDIM;
#pragma unroll
            for (int f = 0; f < 8; ++f) kreg[f] = load8<ISBF>(km, kn + f * 32);
        }

        // mask for (q=qrow, kk = kk0 + g*4 + r)
        int msk[4];
        if (mflag) {
            const int4 mm = *(const int4*)((const int*)mask + moff + kk0);
            msk[0] = mm.x; msk[1] = mm.y; msk[2] = mm.z; msk[3] = mm.w;
        } else {
            const unsigned mm = *(const unsigned*)((const unsigned char*)mask + moff + kk0);
            msk[0] = mm & 255u; msk[1] = (mm >> 8) & 255u;
            msk[2] = (mm >> 16) & 255u; msk[3] = (mm >> 24) & 255u;
        }

        // cross-wave reduce of partial S^T
        *(f32x4*)&Spart[(w * 64 + lane) * 4] = sp;
        __syncthreads();
        const f32x4 s0 = *(const f32x4*)&Spart[lane * 4];
        const f32x4 s1 = *(const f32x4*)&Spart[(64 + lane) * 4];
        const f32x4 s2 = *(const f32x4*)&Spart[(128 + lane) * 4];
        const f32x4 s3 = *(const f32x4*)&Spart[(192 + lane) * 4];

        float sc[4];
#pragma unroll
        for (int r = 0; r < 4; ++r) {
            const float sv = (s0[r] + s1[r] + s2[r] + s3[r]) * QKSCALE;
            sc[r] = msk[r] ? NEGINF : sv;
        }

        // online softmax; row = q = lo, replicated across the 4 lane-groups
        float tmax = fmaxf(fmaxf(sc[0], sc[1]), fmaxf(sc[2], sc[3]));
        tmax = fmaxf(tmax, __shfl_xor(tmax, 16));
        tmax = fmaxf(tmax, __shfl_xor(tmax, 32));
        const float m_old = m_run;
        const float m_new = fmaxf(m_old, tmax);
        float p[4];
#pragma unroll
        for (int r = 0; r < 4; ++r) p[r] = __expf(sc[r] - m_new);
        float ts = p[0] + p[1] + p[2] + p[3];
        ts += __shfl_xor(ts, 16);
        ts += __shfl_xor(ts, 32);
        const float alpha = __expf(m_old - m_new);
        l_run = l_run * alpha + ts;
        m_run = m_new;

        if (!__all(m_new == m_old)) {   // exact skip-rescale (alpha==1 everywhere)
            float ar[4];
#pragma unroll
            for (int r = 0; r < 4; ++r) ar[r] = __shfl(alpha, g * 4 + r);
#pragma unroll
            for (int ch = 0; ch < 16; ++ch) {
#pragma unroll
                for (int r = 0; r < 4; ++r) acc[ch][r] = acc[ch][r] * ar[r];
            }
        }

        // P -> bf16 A-frag for PV (layout already matches: A[q=lo][kk=g*4+r])
        bf16x4v pf;
#pragma unroll
        for (int r = 0; r < 4; ++r) pf[r] = f2bf(p[r]);

        // PV: acc[q][d] += P * V ; B-frag = V[kk0+g*4+j][dcol] via padded LDS gathers
#pragma unroll
        for (int ch = 0; ch < 16; ++ch) {
            const int dcol = w * 256 + ch * 16 + lo;
            bf16x4v vf;
            vf[0] = Vt[(g * 4 + 0) * 1028 + dcol];
            vf[1] = Vt[(g * 4 + 1) * 1028 + dcol];
            vf[2] = Vt[(g * 4 + 2) * 1028 + dcol];
            vf[3] = Vt[(g * 4 + 3) * 1028 + dcol];
            acc[ch] = __builtin_amdgcn_mfma_f32_16x16x16bf16_1k(pf, vf, acc[ch], 0, 0, 0);
        }
        __syncthreads();
    }

    // normalize and store Atted^T[b][d][q] (bf16 in ws)
    float inv[4];
#pragma unroll
    for (int r = 0; r < 4; ++r) inv[r] = 1.f / __shfl(l_run, g * 4 + r);
#pragma unroll
    for (int ch = 0; ch < 16; ++ch) {
        const int dcol = w * 256 + ch * 16 + lo;
        short* ob = attedT + ((size_t)b * DDIM + dcol) * LQS + qt * 16 + g * 4;
#pragma unroll
        for (int r = 0; r < 4; ++r) ob[r] = f2bf(acc[ch][r] * inv[r]);
    }
}

__global__ __launch_bounds__(256) void attn_kernel(
    const void* __restrict__ qm, const void* __restrict__ km,
    const void* __restrict__ vm, const void* __restrict__ mask,
    const int* __restrict__ flagp, short* __restrict__ attedT) {
    __shared__ __align__(16) short Vt[16 * 1028];
    __shared__ __align__(16) float Spart[4 * 64 * 4];
    const int mflag = flagp[0], isbf = flagp[1];
    if (isbf) attn_body<1>(qm, km, vm, mask, mflag, attedT, Vt, Spart);
    else      attn_body<0>(qm, km, vm, mask, mflag, attedT, Vt, Spart);
}

// ---- merge: Out[b][d][o] = sum_l AttedT[b][d][l] * W[o][l] + bias[o]
template <int ISBF>
__device__ __forceinline__ void merge_body(
    const short* __restrict__ attedT, const void* __restrict__ Wm,
    const void* __restrict__ bias, void* __restrict__ out) {

    const int tid  = threadIdx.x;
    const int w    = tid >> 6;
    const int lane = tid & 63;
    const int lo   = lane & 15;
    const int g    = lane >> 4;
    const int b  = blockIdx.x >> 6;
    const int dt = (blockIdx.x >> 3) & 7;
    const int ot = blockIdx.x & 7;
    const int wr = w >> 1, wc = w & 1;
    const int d0 = dt * 128 + wr * 64;
    const int o0 = ot * 128 + wc * 64;

    f32x4 acc[4][4];
#pragma unroll
    for (int mf = 0; mf < 4; ++mf)
#pragma unroll
        for (int nf = 0; nf < 4; ++nf) acc[mf][nf] = (f32x4){0.f, 0.f, 0.f, 0.f};

    const short* abase = attedT + ((size_t)b * DDIM + d0 + lo) * LQS + g * 8;
    const size_t bbase = (size_t)(o0 + lo) * DDIM + g * 8;

    for (int kt = 0; kt < 32; ++kt) {
        bf16x8 af[4], bfr[4];
#pragma unroll
        for (int mf = 0; mf < 4; ++mf)
            af[mf] = *(const bf16x8*)(abase + (size_t)mf * 16 * LQS + kt * 32);
#pragma unroll
        for (int nf = 0; nf < 4; ++nf)
            bfr[nf] = load8<ISBF>(Wm, bbase + (size_t)nf * 16 * DDIM + kt * 32);
#pragma unroll
        for (int mf = 0; mf < 4; ++mf) {
#pragma unroll
            for (int nf = 0; nf < 4; ++nf)
                acc[mf][nf] = __builtin_amdgcn_mfma_f32_16x16x32_bf16(
                    af[mf], bfr[nf], acc[mf][nf], 0, 0, 0);
        }
    }

#pragma unroll
    for (int nf = 0; nf < 4; ++nf) {
        const float bv = ISBF ? bf2f(((const short*)bias)[o0 + nf * 16 + lo])
                              : ((const float*)bias)[o0 + nf * 16 + lo];
#pragma unroll
        for (int mf = 0; mf < 4; ++mf) {
#pragma unroll
            for (int r = 0; r < 4; ++r) {
                const size_t oaddr =
                    ((size_t)b * DDIM + d0 + mf * 16 + g * 4 + r) * 1024 + o0 + nf * 16 + lo;
                const float val = acc[mf][nf][r] + bv;
                if constexpr (ISBF) ((short*)out)[oaddr] = f2bf(val);
                else                ((float*)out)[oaddr] = val;
            }
        }
    }
}

__global__ __launch_bounds__(256) void merge_kernel(
    const short* __restrict__ attedT, const void* __restrict__ Wm,
    const void* __restrict__ bias, void* __restrict__ out,
    const int* __restrict__ flagp) {
    if (flagp[1]) merge_body<1>(attedT, Wm, bias, out);
    else          merge_body<0>(attedT, Wm, bias, out);
}

extern "C" void kernel_launch(void* const* d_in, const int* in_sizes, int n_in,
                              void* d_out, int out_size, void* d_ws, size_t ws_size,
                              hipStream_t stream) {
    // setup_inputs order: v, k, q, mask, W_merge, b_merge
    const void* v    = d_in[0];
    const void* k    = d_in[1];
    const void* q    = d_in[2];
    const void* mask = d_in[3];
    const void* Wm   = d_in[4];
    const void* bias = d_in[5];

    const size_t atted_bytes = (size_t)NBATCH * DDIM * LQS * 2;  // 16.78 MB
    if (ws_size < 4096 + atted_bytes) return;  // fail cleanly rather than corrupt

    int*   flags  = (int*)d_ws;
    short* attedT = (short*)((char*)d_ws + 4096);

    hipLaunchKernelGGL(detect_kernel, dim3(1), dim3(64), 0, stream,
                       (const unsigned char*)mask, (const unsigned char*)v, flags);
    hipLaunchKernelGGL(attn_kernel, dim3(512), dim3(256), 0, stream,
                       q, k, v, mask, flags, attedT);
    hipLaunchKernelGGL(merge_kernel, dim3(512), dim3(256), 0, stream,
                       attedT, Wm, bias, d_out, flags);
}

// Round 4
// 887.282 us; speedup vs baseline: 2.6538x; 2.6538x over previous
//
#include <hip/hip_runtime.h>
#include <stdint.h>

typedef __attribute__((ext_vector_type(4))) float f32x4;
typedef __attribute__((ext_vector_type(8))) short bf16x8;
typedef __attribute__((ext_vector_type(4))) short bf16x4v;
typedef __attribute__((ext_vector_type(4))) unsigned int u32x4;

#define NBATCH 8
#define LQS    1024
#define LKS    4096
#define DDIM   1024
#define QKSCALE 0.03125f
#define NEGINF -1000000000.0f

__device__ __forceinline__ short f2bf(float x) {  // round-to-nearest-even
    unsigned u = __builtin_bit_cast(unsigned, x);
    unsigned r = (u + 0x7fffu + ((u >> 16) & 1u)) >> 16;
    return (short)r;
}

// 8 contiguous fp32 -> bf16x8 via v_perm (truncation) — proven in r3 merge @~690TF
__device__ __forceinline__ bf16x8 cvt8(const float* f) {
    const u32x4* u = (const u32x4*)f;
    const u32x4 a = u[0], b = u[1];
    union { unsigned w[4]; bf16x8 v; } c;
    c.w[0] = __builtin_amdgcn_perm(a[1], a[0], 0x07060302u);
    c.w[1] = __builtin_amdgcn_perm(a[3], a[2], 0x07060302u);
    c.w[2] = __builtin_amdgcn_perm(b[1], b[0], 0x07060302u);
    c.w[3] = __builtin_amdgcn_perm(b[3], b[2], 0x07060302u);
    return c.v;
}

// ---- mask dtype detection: int32 0/1 has all bytes at off%4!=0 == 0 ----
__global__ void detect_kernel(const unsigned char* __restrict__ mb,
                              int* __restrict__ flags) {
    if (threadIdx.x != 0 || blockIdx.x != 0) return;
    int is_i32 = 1;
    for (int i = 0; i < 256; ++i) {
        if ((i & 3) != 0 && mb[i] != 0) { is_i32 = 0; break; }
    }
    flags[0] = is_i32;
}

// ---- transpose V[k][4096->d 1024] fp32 -> VT[d][k] bf16, 64x64 tiles ----
__global__ __launch_bounds__(256) void transv_kernel(
    const float* __restrict__ V, short* __restrict__ VT) {
    __shared__ short LDSt[64 * 72];  // [d][k], rows 144B (16B-aligned)
    const int tid = threadIdx.x;
    const int cb  = blockIdx.x >> 10;           // chunk-batch
    const int t   = blockIdx.x & 1023;
    const int kt  = t >> 4, dt = t & 15;
    const int k0  = kt * 64, d0 = dt * 64;
    const float* Vb  = V  + (size_t)cb * LKS * DDIM;
    short*       VTb = VT + (size_t)cb * ((size_t)DDIM * LKS);

    const int r  = tid >> 4;            // 0..15
    const int cp = (tid & 15) * 4;      // 0..60
#pragma unroll
    for (int rr = 0; rr < 4; ++rr) {
        const int row = rr * 16 + r;    // k within tile
        const f32x4 v = *(const f32x4*)(Vb + (size_t)(k0 + row) * DDIM + d0 + cp);
#pragma unroll
        for (int i = 0; i < 4; ++i) LDSt[(cp + i) * 72 + row] = f2bf(v[i]);
    }
    __syncthreads();
    const int dr = tid >> 2;            // 0..63
    const int kq = (tid & 3) * 16;      // 0,16,32,48
    const bf16x8 o0 = *(const bf16x8*)&LDSt[dr * 72 + kq];
    const bf16x8 o1 = *(const bf16x8*)&LDSt[dr * 72 + kq + 8];
    short* dst = VTb + (size_t)(d0 + dr) * LKS + k0 + kq;
    *(bf16x8*)dst       = o0;
    *(bf16x8*)(dst + 8) = o1;
}

// ---- gemm1: S[q][k] = scale * sum_d Q[q][d] K[k][d]  (fp32 in, fp32 out) ----
__global__ __launch_bounds__(256) void gemm1_kernel(
    const float* __restrict__ Q, const float* __restrict__ K,
    float* __restrict__ S) {
    const int tid = threadIdx.x, w = tid >> 6, lane = tid & 63;
    const int lo = lane & 15, g = lane >> 4;
    const int cb = blockIdx.x >> 8;
    const int t  = blockIdx.x & 255;
    const int qt = t >> 5, ktile = t & 31;
    const int wr = w >> 1, wc = w & 1;
    const int q0 = qt * 128 + wr * 64;
    const int k0 = ktile * 128 + wc * 64;

    const float* Qb = Q + (size_t)cb * LQS * DDIM;
    const float* Kb = K + (size_t)cb * LKS * DDIM;
    float*       Sb = S + (size_t)cb * ((size_t)LQS * LKS);

    f32x4 acc[4][4];
#pragma unroll
    for (int mf = 0; mf < 4; ++mf)
#pragma unroll
        for (int nf = 0; nf < 4; ++nf) acc[mf][nf] = (f32x4){0.f, 0.f, 0.f, 0.f};

    const float* abase = Qb + (size_t)(q0 + lo) * DDIM + g * 8;
    const float* bbase = Kb + (size_t)(k0 + lo) * DDIM + g * 8;

    for (int kt = 0; kt < 32; ++kt) {
        bf16x8 af[4], bf[4];
#pragma unroll
        for (int mf = 0; mf < 4; ++mf)
            af[mf] = cvt8(abase + (size_t)mf * 16 * DDIM + kt * 32);
#pragma unroll
        for (int nf = 0; nf < 4; ++nf)
            bf[nf] = cvt8(bbase + (size_t)nf * 16 * DDIM + kt * 32);
#pragma unroll
        for (int mf = 0; mf < 4; ++mf)
#pragma unroll
            for (int nf = 0; nf < 4; ++nf)
                acc[mf][nf] = __builtin_amdgcn_mfma_f32_16x16x32_bf16(
                    af[mf], bf[nf], acc[mf][nf], 0, 0, 0);
    }

#pragma unroll
    for (int mf = 0; mf < 4; ++mf)
#pragma unroll
        for (int nf = 0; nf < 4; ++nf)
#pragma unroll
            for (int r = 0; r < 4; ++r)
                Sb[(size_t)(q0 + mf * 16 + g * 4 + r) * LKS + k0 + nf * 16 + lo] =
                    acc[mf][nf][r] * QKSCALE;
}

// ---- softmax: one block per q-row; masked; writes normalized P bf16 in-place
// P row q lives at (short*)(S + row*4096) i.e. fp32 row stride (8192 shorts).
__global__ __launch_bounds__(256) void softmax_kernel(
    float* __restrict__ S, const void* __restrict__ mask,
    const int* __restrict__ flags, int c0) {
    __shared__ float red[4];
    const int tid = threadIdx.x, w = tid >> 6, lane = tid & 63;
    const int cb = blockIdx.x >> 10;
    const int q  = blockIdx.x & 1023;
    const int mflag = flags[0];

    float* Srow = S + ((size_t)cb * LQS + q) * LKS;
    const size_t roff = ((size_t)(c0 + cb) * LQS + q) * LKS;

    float sc[16];
#pragma unroll
    for (int j = 0; j < 4; ++j) {
        const f32x4 sv = ((const f32x4*)Srow)[j * 256 + tid];
        int m0, m1, m2, m3;
        if (mflag) {
            const int4 mv = ((const int4*)((const int*)mask + roff))[j * 256 + tid];
            m0 = mv.x; m1 = mv.y; m2 = mv.z; m3 = mv.w;
        } else {
            const uchar4 mv = ((const uchar4*)((const unsigned char*)mask + roff))[j * 256 + tid];
            m0 = mv.x; m1 = mv.y; m2 = mv.z; m3 = mv.w;
        }
        sc[j * 4 + 0] = m0 ? NEGINF : sv[0];
        sc[j * 4 + 1] = m1 ? NEGINF : sv[1];
        sc[j * 4 + 2] = m2 ? NEGINF : sv[2];
        sc[j * 4 + 3] = m3 ? NEGINF : sv[3];
    }

    float lm = -INFINITY;
#pragma unroll
    for (int i = 0; i < 16; ++i) lm = fmaxf(lm, sc[i]);
#pragma unroll
    for (int off = 1; off < 64; off <<= 1) lm = fmaxf(lm, __shfl_xor(lm, off));
    if (lane == 0) red[w] = lm;
    __syncthreads();
    const float m = fmaxf(fmaxf(red[0], red[1]), fmaxf(red[2], red[3]));

    float p[16], ls = 0.f;
#pragma unroll
    for (int i = 0; i < 16; ++i) { p[i] = __expf(sc[i] - m); ls += p[i]; }
#pragma unroll
    for (int off = 1; off < 64; off <<= 1) ls += __shfl_xor(ls, off);
    __syncthreads();
    if (lane == 0) red[w] = ls;
    __syncthreads();
    const float inv = 1.f / (red[0] + red[1] + red[2] + red[3]);

    short* Prow = (short*)Srow;
#pragma unroll
    for (int j = 0; j < 4; ++j) {
        bf16x4v pv;
#pragma unroll
        for (int i = 0; i < 4; ++i) pv[i] = f2bf(p[j * 4 + i] * inv);
        ((bf16x4v*)Prow)[j * 256 + tid] = pv;
    }
}

// ---- gemm2: attedT[d][q] = sum_k VT[d][k] * P[q][k]  (bf16 in, bf16 out) ----
__global__ __launch_bounds__(256) void gemm2_kernel(
    const short* __restrict__ VT, const float* __restrict__ S,
    short* __restrict__ attedT) {
    const int tid = threadIdx.x, w = tid >> 6, lane = tid & 63;
    const int lo = lane & 15, g = lane >> 4;
    const int cb = blockIdx.x >> 6;
    const int t  = blockIdx.x & 63;
    const int dt = t >> 3, qt = t & 7;
    const int wr = w >> 1, wc = w & 1;
    const int d0 = dt * 128 + wr * 64;
    const int q0 = qt * 128 + wc * 64;

    const short* VTb = VT + (size_t)cb * ((size_t)DDIM * LKS);
    const short* Pb  = (const short*)(S + (size_t)cb * ((size_t)LQS * LKS));
    short*       Ab  = attedT + (size_t)cb * ((size_t)DDIM * LQS);

    f32x4 acc[4][4];
#pragma unroll
    for (int mf = 0; mf < 4; ++mf)
#pragma unroll
        for (int nf = 0; nf < 4; ++nf) acc[mf][nf] = (f32x4){0.f, 0.f, 0.f, 0.f};

    const short* abase = VTb + (size_t)(d0 + lo) * LKS + g * 8;
    const short* bbase = Pb + (size_t)(q0 + lo) * (2 * LKS) + g * 8;  // P row stride 8192

    for (int kt = 0; kt < 128; ++kt) {
        bf16x8 af[4], bf[4];
#pragma unroll
        for (int mf = 0; mf < 4; ++mf)
            af[mf] = *(const bf16x8*)(abase + (size_t)mf * 16 * LKS + kt * 32);
#pragma unroll
        for (int nf = 0; nf < 4; ++nf)
            bf[nf] = *(const bf16x8*)(bbase + (size_t)nf * 16 * (2 * LKS) + kt * 32);
#pragma unroll
        for (int mf = 0; mf < 4; ++mf)
#pragma unroll
            for (int nf = 0; nf < 4; ++nf)
                acc[mf][nf] = __builtin_amdgcn_mfma_f32_16x16x32_bf16(
                    af[mf], bf[nf], acc[mf][nf], 0, 0, 0);
    }

#pragma unroll
    for (int mf = 0; mf < 4; ++mf)
#pragma unroll
        for (int nf = 0; nf < 4; ++nf)
#pragma unroll
            for (int r = 0; r < 4; ++r)
                Ab[(size_t)(d0 + mf * 16 + g * 4 + r) * LQS + q0 + nf * 16 + lo] =
                    f2bf(acc[mf][nf][r]);
}

// ---- merge: out[b][d][o] = sum_l attedT[d][l] * W[o][l] + bias[o] (fp32 out)
__global__ __launch_bounds__(256) void merge_kernel(
    const short* __restrict__ attedT, const float* __restrict__ Wm,
    const float* __restrict__ bias, float* __restrict__ out) {
    const int tid = threadIdx.x, w = tid >> 6, lane = tid & 63;
    const int lo = lane & 15, g = lane >> 4;
    const int cb = blockIdx.x >> 6;
    const int t  = blockIdx.x & 63;
    const int dt = t >> 3, ot = t & 7;
    const int wr = w >> 1, wc = w & 1;
    const int d0 = dt * 128 + wr * 64;
    const int o0 = ot * 128 + wc * 64;

    const short* Ab = attedT + (size_t)cb * ((size_t)DDIM * LQS);
    float*       Ob = out + (size_t)cb * ((size_t)DDIM * LQS);

    f32x4 acc[4][4];
#pragma unroll
    for (int mf = 0; mf < 4; ++mf)
#pragma unroll
        for (int nf = 0; nf < 4; ++nf) acc[mf][nf] = (f32x4){0.f, 0.f, 0.f, 0.f};

    const short* abase = Ab + (size_t)(d0 + lo) * LQS + g * 8;
    const float* bbase = Wm + (size_t)(o0 + lo) * DDIM + g * 8;

    for (int kt = 0; kt < 32; ++kt) {
        bf16x8 af[4], bf[4];
#pragma unroll
        for (int mf = 0; mf < 4; ++mf)
            af[mf] = *(const bf16x8*)(abase + (size_t)mf * 16 * LQS + kt * 32);
#pragma unroll
        for (int nf = 0; nf < 4; ++nf)
            bf[nf] = cvt8(bbase + (size_t)nf * 16 * DDIM + kt * 32);
#pragma unroll
        for (int mf = 0; mf < 4; ++mf)
#pragma unroll
            for (int nf = 0; nf < 4; ++nf)
                acc[mf][nf] = __builtin_amdgcn_mfma_f32_16x16x32_bf16(
                    af[mf], bf[nf], acc[mf][nf], 0, 0, 0);
    }

#pragma unroll
    for (int nf = 0; nf < 4; ++nf) {
        const float bv = bias[o0 + nf * 16 + lo];
#pragma unroll
        for (int mf = 0; mf < 4; ++mf)
#pragma unroll
            for (int r = 0; r < 4; ++r)
                Ob[(size_t)(d0 + mf * 16 + g * 4 + r) * DDIM + o0 + nf * 16 + lo] =
                    acc[mf][nf][r] + bv;
    }
}

extern "C" void kernel_launch(void* const* d_in, const int* in_sizes, int n_in,
                              void* d_out, int out_size, void* d_ws, size_t ws_size,
                              hipStream_t stream) {
    // setup_inputs order: v, k, q, mask, W_merge, b_merge (all fp32; mask i32/u8)
    const float* v    = (const float*)d_in[0];
    const float* k    = (const float*)d_in[1];
    const float* q    = (const float*)d_in[2];
    const void*  mask = d_in[3];
    const float* Wm   = (const float*)d_in[4];
    const float* bias = (const float*)d_in[5];
    float* out = (float*)d_out;

    // per-batch ws: S 16MiB + VT 8MiB + attedT 2MiB = 26MiB; choose chunk size
    const size_t per  = 26ull << 20;
    const size_t base = 4096;
    int nb = 0;
    for (int cand = 8; cand >= 1; cand >>= 1)
        if (base + (size_t)cand * per <= ws_size) { nb = cand; break; }
    if (!nb) return;  // ws too small — fail loudly via wrong output

    int*   flags  = (int*)d_ws;
    char*  arena  = (char*)d_ws + base;
    float* Sbuf   = (float*)arena;                                  // nb*16MiB
    short* VTbuf  = (short*)(arena + ((size_t)nb << 24));           // nb*8MiB
    short* attedT = (short*)(arena + ((size_t)nb << 24) + ((size_t)nb << 23));  // nb*2MiB

    hipLaunchKernelGGL(detect_kernel, dim3(1), dim3(64), 0, stream,
                       (const unsigned char*)mask, flags);

    for (int c0 = 0; c0 < NBATCH; c0 += nb) {
        const float* vc = v + (size_t)c0 * LKS * DDIM;
        const float* kc = k + (size_t)c0 * LKS * DDIM;
        const float* qc = q + (size_t)c0 * LQS * DDIM;
        float*       oc = out + (size_t)c0 * DDIM * LQS;

        hipLaunchKernelGGL(transv_kernel, dim3(nb * 1024), dim3(256), 0, stream,
                           vc, VTbuf);
        hipLaunchKernelGGL(gemm1_kernel, dim3(nb * 256), dim3(256), 0, stream,
                           qc, kc, Sbuf);
        hipLaunchKernelGGL(softmax_kernel, dim3(nb * 1024), dim3(256), 0, stream,
                           Sbuf, mask, flags, c0);
        hipLaunchKernelGGL(gemm2_kernel, dim3(nb * 64), dim3(256), 0, stream,
                           VTbuf, Sbuf, attedT);
        hipLaunchKernelGGL(merge_kernel, dim3(nb * 64), dim3(256), 0, stream,
                           attedT, Wm, bias, oc);
    }
}

// Round 5
// 709.628 us; speedup vs baseline: 3.3182x; 1.2503x over previous
//
#include <hip/hip_runtime.h>
#include <stdint.h>

typedef __attribute__((ext_vector_type(4))) float f32x4;
typedef __attribute__((ext_vector_type(8))) short bf16x8;
typedef __attribute__((ext_vector_type(4))) short bf16x4v;
typedef __attribute__((ext_vector_type(4))) unsigned int u32x4;

#define NBATCH 8
#define LQS    1024
#define LKS    4096
#define DDIM   1024
#define QKSCALE 0.03125f
#define NEGINF -1000000000.0f

__device__ __forceinline__ short f2bf(float x) {  // round-to-nearest-even
    unsigned u = __builtin_bit_cast(unsigned, x);
    unsigned r = (u + 0x7fffu + ((u >> 16) & 1u)) >> 16;
    return (short)r;
}

// 8 contiguous fp32 -> bf16x8 via v_perm (truncation)
__device__ __forceinline__ bf16x8 cvt8(const float* f) {
    const u32x4* u = (const u32x4*)f;
    const u32x4 a = u[0], b = u[1];
    union { unsigned w[4]; bf16x8 v; } c;
    c.w[0] = __builtin_amdgcn_perm(a[1], a[0], 0x07060302u);
    c.w[1] = __builtin_amdgcn_perm(a[3], a[2], 0x07060302u);
    c.w[2] = __builtin_amdgcn_perm(b[1], b[0], 0x07060302u);
    c.w[3] = __builtin_amdgcn_perm(b[3], b[2], 0x07060302u);
    return c.v;
}

// ---- mask dtype detection ----
__global__ void detect_kernel(const unsigned char* __restrict__ mb,
                              int* __restrict__ flags) {
    if (threadIdx.x != 0 || blockIdx.x != 0) return;
    int is_i32 = 1;
    for (int i = 0; i < 256; ++i) {
        if ((i & 3) != 0 && mb[i] != 0) { is_i32 = 0; break; }
    }
    flags[0] = is_i32;
}

// ---- bulk fp32 -> bf16 conversion, 8 elems/thread, grid-stride ----
__global__ __launch_bounds__(256) void cvt_kernel(
    const float* __restrict__ src, short* __restrict__ dst, int n8) {
    const int stride = gridDim.x * 256;
    for (int i = blockIdx.x * 256 + threadIdx.x; i < n8; i += stride)
        ((bf16x8*)dst)[i] = cvt8(src + (size_t)i * 8);
}

// ---- transpose V[k][d] fp32 -> VT[d][k] bf16, 64x64 tiles ----
__global__ __launch_bounds__(256) void transv_kernel(
    const float* __restrict__ V, short* __restrict__ VT) {
    __shared__ short LDSt[64 * 72];
    const int tid = threadIdx.x;
    const int cb  = blockIdx.x >> 10;
    const int t   = blockIdx.x & 1023;
    const int kt  = t >> 4, dt = t & 15;
    const int k0  = kt * 64, d0 = dt * 64;
    const float* Vb  = V  + (size_t)cb * LKS * DDIM;
    short*       VTb = VT + (size_t)cb * ((size_t)DDIM * LKS);

    const int r  = tid >> 4;
    const int cp = (tid & 15) * 4;
#pragma unroll
    for (int rr = 0; rr < 4; ++rr) {
        const int row = rr * 16 + r;
        const f32x4 v = *(const f32x4*)(Vb + (size_t)(k0 + row) * DDIM + d0 + cp);
#pragma unroll
        for (int i = 0; i < 4; ++i) LDSt[(cp + i) * 72 + row] = f2bf(v[i]);
    }
    __syncthreads();
    const int dr = tid >> 2;
    const int kq = (tid & 3) * 16;
    const bf16x8 o0 = *(const bf16x8*)&LDSt[dr * 72 + kq];
    const bf16x8 o1 = *(const bf16x8*)&LDSt[dr * 72 + kq + 8];
    short* dst = VTb + (size_t)(d0 + dr) * LKS + k0 + kq;
    *(bf16x8*)dst       = o0;
    *(bf16x8*)(dst + 8) = o1;
}

// ---- gemm1: S[q][k] = scale * sum_d Qb[q][d] Kb[k][d]  (bf16 in, fp32 out) ----
__global__ __launch_bounds__(256) void gemm1_kernel(
    const short* __restrict__ Qb, const short* __restrict__ Kb,
    float* __restrict__ S) {
    const int tid = threadIdx.x, w = tid >> 6, lane = tid & 63;
    const int lo = lane & 15, g = lane >> 4;
    const int cb = blockIdx.x >> 8;
    const int t  = blockIdx.x & 255;
    const int qt = t >> 5, ktile = t & 31;
    const int wr = w >> 1, wc = w & 1;
    const int q0 = qt * 128 + wr * 64;
    const int k0 = ktile * 128 + wc * 64;

    const short* Ap = Qb + (size_t)cb * LQS * DDIM + (size_t)(q0 + lo) * DDIM + g * 8;
    const short* Bp = Kb + (size_t)cb * LKS * DDIM + (size_t)(k0 + lo) * DDIM + g * 8;
    float*       Sb = S + (size_t)cb * ((size_t)LQS * LKS);

    f32x4 acc[4][4];
#pragma unroll
    for (int mf = 0; mf < 4; ++mf)
#pragma unroll
        for (int nf = 0; nf < 4; ++nf) acc[mf][nf] = (f32x4){0.f, 0.f, 0.f, 0.f};

    auto lda = [&](bf16x8* d, int kk) {
#pragma unroll
        for (int mf = 0; mf < 4; ++mf)
            d[mf] = *(const bf16x8*)(Ap + (size_t)mf * 16 * DDIM + kk * 32);
    };
    auto ldb = [&](bf16x8* d, int kk) {
#pragma unroll
        for (int nf = 0; nf < 4; ++nf)
            d[nf] = *(const bf16x8*)(Bp + (size_t)nf * 16 * DDIM + kk * 32);
    };
    auto mm = [&](bf16x8* a, bf16x8* b) {
#pragma unroll
        for (int mf = 0; mf < 4; ++mf)
#pragma unroll
            for (int nf = 0; nf < 4; ++nf)
                acc[mf][nf] = __builtin_amdgcn_mfma_f32_16x16x32_bf16(
                    a[mf], b[nf], acc[mf][nf], 0, 0, 0);
    };

    bf16x8 a0[4], b0[4], a1[4], b1[4];
    lda(a0, 0); ldb(b0, 0);
    for (int kt2 = 0; kt2 < 16; ++kt2) {
        const int k1 = 2 * kt2 + 1;
        lda(a1, k1); ldb(b1, k1);
        mm(a0, b0);
        const int k2 = (2 * kt2 + 2 < 32) ? 2 * kt2 + 2 : 0;
        lda(a0, k2); ldb(b0, k2);
        mm(a1, b1);
    }

#pragma unroll
    for (int mf = 0; mf < 4; ++mf)
#pragma unroll
        for (int nf = 0; nf < 4; ++nf)
#pragma unroll
            for (int r = 0; r < 4; ++r)
                Sb[(size_t)(q0 + mf * 16 + g * 4 + r) * LKS + k0 + nf * 16 + lo] =
                    acc[mf][nf][r] * QKSCALE;
}

// ---- softmax: one block per q-row; masked; writes normalized P bf16 in-place
__global__ __launch_bounds__(256) void softmax_kernel(
    float* __restrict__ S, const void* __restrict__ mask,
    const int* __restrict__ flags, int c0) {
    __shared__ float red[4];
    const int tid = threadIdx.x, w = tid >> 6, lane = tid & 63;
    const int cb = blockIdx.x >> 10;
    const int q  = blockIdx.x & 1023;
    const int mflag = flags[0];

    float* Srow = S + ((size_t)cb * LQS + q) * LKS;
    const size_t roff = ((size_t)(c0 + cb) * LQS + q) * LKS;

    float sc[16];
#pragma unroll
    for (int j = 0; j < 4; ++j) {
        const f32x4 sv = ((const f32x4*)Srow)[j * 256 + tid];
        int m0, m1, m2, m3;
        if (mflag) {
            const int4 mv = ((const int4*)((const int*)mask + roff))[j * 256 + tid];
            m0 = mv.x; m1 = mv.y; m2 = mv.z; m3 = mv.w;
        } else {
            const uchar4 mv = ((const uchar4*)((const unsigned char*)mask + roff))[j * 256 + tid];
            m0 = mv.x; m1 = mv.y; m2 = mv.z; m3 = mv.w;
        }
        sc[j * 4 + 0] = m0 ? NEGINF : sv[0];
        sc[j * 4 + 1] = m1 ? NEGINF : sv[1];
        sc[j * 4 + 2] = m2 ? NEGINF : sv[2];
        sc[j * 4 + 3] = m3 ? NEGINF : sv[3];
    }

    float lm = -INFINITY;
#pragma unroll
    for (int i = 0; i < 16; ++i) lm = fmaxf(lm, sc[i]);
#pragma unroll
    for (int off = 1; off < 64; off <<= 1) lm = fmaxf(lm, __shfl_xor(lm, off));
    if (lane == 0) red[w] = lm;
    __syncthreads();
    const float m = fmaxf(fmaxf(red[0], red[1]), fmaxf(red[2], red[3]));

    float p[16], ls = 0.f;
#pragma unroll
    for (int i = 0; i < 16; ++i) { p[i] = __expf(sc[i] - m); ls += p[i]; }
#pragma unroll
    for (int off = 1; off < 64; off <<= 1) ls += __shfl_xor(ls, off);
    __syncthreads();
    if (lane == 0) red[w] = ls;
    __syncthreads();
    const float inv = 1.f / (red[0] + red[1] + red[2] + red[3]);

    short* Prow = (short*)Srow;
#pragma unroll
    for (int j = 0; j < 4; ++j) {
        bf16x4v pv;
#pragma unroll
        for (int i = 0; i < 4; ++i) pv[i] = f2bf(p[j * 4 + i] * inv);
        ((bf16x4v*)Prow)[j * 256 + tid] = pv;
    }
}

// ---- gemm2: attedT[d][q] = sum_k VT[d][k] * P[q][k]  (bf16 in, bf16 out) ----
__global__ __launch_bounds__(256) void gemm2_kernel(
    const short* __restrict__ VT, const float* __restrict__ S,
    short* __restrict__ attedT) {
    const int tid = threadIdx.x, w = tid >> 6, lane = tid & 63;
    const int lo = lane & 15, g = lane >> 4;
    const int cb = blockIdx.x >> 6;
    const int t  = blockIdx.x & 63;
    const int dt = t >> 3, qt = t & 7;
    const int wr = w >> 1, wc = w & 1;
    const int d0 = dt * 128 + wr * 64;
    const int q0 = qt * 128 + wc * 64;

    const short* Ap = VT + (size_t)cb * ((size_t)DDIM * LKS) + (size_t)(d0 + lo) * LKS + g * 8;
    const short* Bp = (const short*)(S + (size_t)cb * ((size_t)LQS * LKS))
                      + (size_t)(q0 + lo) * (2 * LKS) + g * 8;   // P row stride 8192
    short* Ab = attedT + (size_t)cb * ((size_t)DDIM * LQS);

    f32x4 acc[4][4];
#pragma unroll
    for (int mf = 0; mf < 4; ++mf)
#pragma unroll
        for (int nf = 0; nf < 4; ++nf) acc[mf][nf] = (f32x4){0.f, 0.f, 0.f, 0.f};

    auto lda = [&](bf16x8* d, int kk) {
#pragma unroll
        for (int mf = 0; mf < 4; ++mf)
            d[mf] = *(const bf16x8*)(Ap + (size_t)mf * 16 * LKS + kk * 32);
    };
    auto ldb = [&](bf16x8* d, int kk) {
#pragma unroll
        for (int nf = 0; nf < 4; ++nf)
            d[nf] = *(const bf16x8*)(Bp + (size_t)nf * 16 * (2 * LKS) + kk * 32);
    };
    auto mm = [&](bf16x8* a, bf16x8* b) {
#pragma unroll
        for (int mf = 0; mf < 4; ++mf)
#pragma unroll
            for (int nf = 0; nf < 4; ++nf)
                acc[mf][nf] = __builtin_amdgcn_mfma_f32_16x16x32_bf16(
                    a[mf], b[nf], acc[mf][nf], 0, 0, 0);
    };

    bf16x8 a0[4], b0[4], a1[4], b1[4];
    lda(a0, 0); ldb(b0, 0);
    for (int kt2 = 0; kt2 < 64; ++kt2) {
        const int k1 = 2 * kt2 + 1;
        lda(a1, k1); ldb(b1, k1);
        mm(a0, b0);
        const int k2 = (2 * kt2 + 2 < 128) ? 2 * kt2 + 2 : 0;
        lda(a0, k2); ldb(b0, k2);
        mm(a1, b1);
    }

#pragma unroll
    for (int mf = 0; mf < 4; ++mf)
#pragma unroll
        for (int nf = 0; nf < 4; ++nf)
#pragma unroll
            for (int r = 0; r < 4; ++r)
                Ab[(size_t)(d0 + mf * 16 + g * 4 + r) * LQS + q0 + nf * 16 + lo] =
                    f2bf(acc[mf][nf][r]);
}

// ---- merge: out[b][d][o] = sum_l attedT[d][l] * Wb[o][l] + bias[o] (fp32 out)
__global__ __launch_bounds__(256) void merge_kernel(
    const short* __restrict__ attedT, const short* __restrict__ Wb,
    const float* __restrict__ bias, float* __restrict__ out) {
    const int tid = threadIdx.x, w = tid >> 6, lane = tid & 63;
    const int lo = lane & 15, g = lane >> 4;
    const int cb = blockIdx.x >> 6;
    const int t  = blockIdx.x & 63;
    const int dt = t >> 3, ot = t & 7;
    const int wr = w >> 1, wc = w & 1;
    const int d0 = dt * 128 + wr * 64;
    const int o0 = ot * 128 + wc * 64;

    const short* Ap = attedT + (size_t)cb * ((size_t)DDIM * LQS) + (size_t)(d0 + lo) * LQS + g * 8;
    const short* Bp = Wb + (size_t)(o0 + lo) * DDIM + g * 8;
    float*       Ob = out + (size_t)cb * ((size_t)DDIM * LQS);

    f32x4 acc[4][4];
#pragma unroll
    for (int mf = 0; mf < 4; ++mf)
#pragma unroll
        for (int nf = 0; nf < 4; ++nf) acc[mf][nf] = (f32x4){0.f, 0.f, 0.f, 0.f};

    auto lda = [&](bf16x8* d, int kk) {
#pragma unroll
        for (int mf = 0; mf < 4; ++mf)
            d[mf] = *(const bf16x8*)(Ap + (size_t)mf * 16 * LQS + kk * 32);
    };
    auto ldb = [&](bf16x8* d, int kk) {
#pragma unroll
        for (int nf = 0; nf < 4; ++nf)
            d[nf] = *(const bf16x8*)(Bp + (size_t)nf * 16 * DDIM + kk * 32);
    };
    auto mm = [&](bf16x8* a, bf16x8* b) {
#pragma unroll
        for (int mf = 0; mf < 4; ++mf)
#pragma unroll
            for (int nf = 0; nf < 4; ++nf)
                acc[mf][nf] = __builtin_amdgcn_mfma_f32_16x16x32_bf16(
                    a[mf], b[nf], acc[mf][nf], 0, 0, 0);
    };

    bf16x8 a0[4], b0[4], a1[4], b1[4];
    lda(a0, 0); ldb(b0, 0);
    for (int kt2 = 0; kt2 < 16; ++kt2) {
        const int k1 = 2 * kt2 + 1;
        lda(a1, k1); ldb(b1, k1);
        mm(a0, b0);
        const int k2 = (2 * kt2 + 2 < 32) ? 2 * kt2 + 2 : 0;
        lda(a0, k2); ldb(b0, k2);
        mm(a1, b1);
    }

#pragma unroll
    for (int nf = 0; nf < 4; ++nf) {
        const float bv = bias[o0 + nf * 16 + lo];
#pragma unroll
        for (int mf = 0; mf < 4; ++mf)
#pragma unroll
            for (int r = 0; r < 4; ++r)
                Ob[(size_t)(d0 + mf * 16 + g * 4 + r) * DDIM + o0 + nf * 16 + lo] =
                    acc[mf][nf][r] + bv;
    }
}

extern "C" void kernel_launch(void* const* d_in, const int* in_sizes, int n_in,
                              void* d_out, int out_size, void* d_ws, size_t ws_size,
                              hipStream_t stream) {
    // setup_inputs order: v, k, q, mask, W_merge, b_merge (fp32; mask i32/u8)
    const float* v    = (const float*)d_in[0];
    const float* k    = (const float*)d_in[1];
    const float* q    = (const float*)d_in[2];
    const void*  mask = d_in[3];
    const float* Wm   = (const float*)d_in[4];
    const float* bias = (const float*)d_in[5];
    float* out = (float*)d_out;

    // layout: flags 4KiB | Wb 2MiB | chunk arena nb*36MiB
    //   chunk: S nb*16MiB | VT nb*8MiB | attedT nb*2MiB | Qb nb*2MiB | Kb nb*8MiB
    const size_t base = 4096 + (2ull << 20);
    int nb = 0;
    for (int cand = 8; cand >= 1; cand >>= 1)
        if (base + (size_t)cand * (36ull << 20) <= ws_size) { nb = cand; break; }
    if (!nb) return;

    int*   flags = (int*)d_ws;
    short* Wb    = (short*)((char*)d_ws + 4096);
    char*  ar    = (char*)d_ws + base;
    float* Sbuf   = (float*)ar;
    short* VTbuf  = (short*)(ar + ((size_t)nb << 24));
    short* attedT = (short*)(ar + ((size_t)nb << 24) + ((size_t)nb << 23));
    short* Qb     = (short*)(ar + ((size_t)nb << 24) + ((size_t)nb << 23) + ((size_t)nb << 21));
    short* Kb     = (short*)(ar + ((size_t)nb << 24) + ((size_t)nb << 23) + 2 * ((size_t)nb << 21));

    hipLaunchKernelGGL(detect_kernel, dim3(1), dim3(64), 0, stream,
                       (const unsigned char*)mask, flags);
    hipLaunchKernelGGL(cvt_kernel, dim3(512), dim3(256), 0, stream,
                       Wm, Wb, (int)(DDIM * DDIM / 8));

    for (int c0 = 0; c0 < NBATCH; c0 += nb) {
        const float* vc = v + (size_t)c0 * LKS * DDIM;
        const float* kc = k + (size_t)c0 * LKS * DDIM;
        const float* qc = q + (size_t)c0 * LQS * DDIM;
        float*       oc = out + (size_t)c0 * DDIM * LQS;

        hipLaunchKernelGGL(cvt_kernel, dim3(1024), dim3(256), 0, stream,
                           qc, Qb, nb * (LQS * DDIM / 8));
        hipLaunchKernelGGL(cvt_kernel, dim3(2048), dim3(256), 0, stream,
                           kc, Kb, nb * (LKS * DDIM / 8));
        hipLaunchKernelGGL(transv_kernel, dim3(nb * 1024), dim3(256), 0, stream,
                           vc, VTbuf);
        hipLaunchKernelGGL(gemm1_kernel, dim3(nb * 256), dim3(256), 0, stream,
                           Qb, Kb, Sbuf);
        hipLaunchKernelGGL(softmax_kernel, dim3(nb * 1024), dim3(256), 0, stream,
                           Sbuf, mask, flags, c0);
        hipLaunchKernelGGL(gemm2_kernel, dim3(nb * 64), dim3(256), 0, stream,
                           VTbuf, Sbuf, attedT);
        hipLaunchKernelGGL(merge_kernel, dim3(nb * 64), dim3(256), 0, stream,
                           attedT, Wb, bias, oc);
    }
}

// Round 6
// 437.560 us; speedup vs baseline: 5.3814x; 1.6218x over previous
//
#include <hip/hip_runtime.h>
#include <stdint.h>

typedef __attribute__((ext_vector_type(4))) float f32x4;
typedef __attribute__((ext_vector_type(8))) short bf16x8;
typedef __attribute__((ext_vector_type(4))) short bf16x4v;
typedef __attribute__((ext_vector_type(4))) unsigned int u32x4;

#define NBATCH 8
#define LQS    1024
#define LKS    4096
#define DDIM   1024
#define QKSCALE 0.03125f
#define NEGINF -1000000000.0f

__device__ __forceinline__ short f2bf(float x) {  // round-to-nearest-even
    unsigned u = __builtin_bit_cast(unsigned, x);
    unsigned r = (u + 0x7fffu + ((u >> 16) & 1u)) >> 16;
    return (short)r;
}

// 8 contiguous fp32 -> bf16x8 via v_perm (truncation)
__device__ __forceinline__ bf16x8 cvt8(const float* f) {
    const u32x4* u = (const u32x4*)f;
    const u32x4 a = u[0], b = u[1];
    union { unsigned w[4]; bf16x8 v; } c;
    c.w[0] = __builtin_amdgcn_perm(a[1], a[0], 0x07060302u);
    c.w[1] = __builtin_amdgcn_perm(a[3], a[2], 0x07060302u);
    c.w[2] = __builtin_amdgcn_perm(b[1], b[0], 0x07060302u);
    c.w[3] = __builtin_amdgcn_perm(b[3], b[2], 0x07060302u);
    return c.v;
}

// async global->LDS, 16B per lane; lds base must be wave-uniform (dest = base + lane*16)
__device__ __forceinline__ void g2l16(const void* g, void* lds) {
    __builtin_amdgcn_global_load_lds(
        (const __attribute__((address_space(1))) unsigned int*)g,
        (__attribute__((address_space(3))) unsigned int*)lds,
        16, 0, 0);
}

// ---- mask dtype detection ----
__global__ void detect_kernel(const unsigned char* __restrict__ mb,
                              int* __restrict__ flags) {
    if (threadIdx.x != 0 || blockIdx.x != 0) return;
    int is_i32 = 1;
    for (int i = 0; i < 256; ++i) {
        if ((i & 3) != 0 && mb[i] != 0) { is_i32 = 0; break; }
    }
    flags[0] = is_i32;
}

// ---- bulk fp32 -> bf16 conversion, 8 elems/thread, grid-stride ----
__global__ __launch_bounds__(256) void cvt_kernel(
    const float* __restrict__ src, short* __restrict__ dst, int n8) {
    const int stride = gridDim.x * 256;
    for (int i = blockIdx.x * 256 + threadIdx.x; i < n8; i += stride)
        ((bf16x8*)dst)[i] = cvt8(src + (size_t)i * 8);
}

// ---- transpose V[k][d] fp32 -> VT[d][k] bf16, 64x64 tiles ----
__global__ __launch_bounds__(256) void transv_kernel(
    const float* __restrict__ V, short* __restrict__ VT) {
    __shared__ short LDSt[64 * 72];
    const int tid = threadIdx.x;
    const int cb  = blockIdx.x >> 10;
    const int t   = blockIdx.x & 1023;
    const int kt  = t >> 4, dt = t & 15;
    const int k0  = kt * 64, d0 = dt * 64;
    const float* Vb  = V  + (size_t)cb * LKS * DDIM;
    short*       VTb = VT + (size_t)cb * ((size_t)DDIM * LKS);

    const int r  = tid >> 4;
    const int cp = (tid & 15) * 4;
#pragma unroll
    for (int rr = 0; rr < 4; ++rr) {
        const int row = rr * 16 + r;
        const f32x4 v = *(const f32x4*)(Vb + (size_t)(k0 + row) * DDIM + d0 + cp);
#pragma unroll
        for (int i = 0; i < 4; ++i) LDSt[(cp + i) * 72 + row] = f2bf(v[i]);
    }
    __syncthreads();
    const int dr = tid >> 2;
    const int kq = (tid & 3) * 16;
    const bf16x8 o0 = *(const bf16x8*)&LDSt[dr * 72 + kq];
    const bf16x8 o1 = *(const bf16x8*)&LDSt[dr * 72 + kq + 8];
    short* dst = VTb + (size_t)(d0 + dr) * LKS + k0 + kq;
    *(bf16x8*)dst       = o0;
    *(bf16x8*)(dst + 8) = o1;
}

// ============ m97-style staged GEMM-BT ============
// C[M][N] = A[M][K]*B[N][K]^T, A/B bf16 k-contiguous. BM=BN=128, BK=32,
// 256 thr / 4 waves, per-wave 64x64 out (4x4 frags). LDS tiles linear [128][32].
// EPI: 0 = fp32 store *scale ; 1 = bf16 store ; 2 = fp32 store + bias
template <int EPI>
__device__ __forceinline__ void gemm_bt(
    const short* __restrict__ A, int lda,
    const short* __restrict__ B, int ldb,
    void* __restrict__ C, int ldc,
    const float* __restrict__ bias,
    int m0, int n0, int nk, float scale,
    short* __restrict__ As, short* __restrict__ Bs) {

    const int tid = threadIdx.x, w = tid >> 6, lane = tid & 63;
    const int lo = lane & 15, g = lane >> 4;
    const int wr = w >> 1, wc = w & 1;

    f32x4 acc[4][4];
#pragma unroll
    for (int mf = 0; mf < 4; ++mf)
#pragma unroll
        for (int nf = 0; nf < 4; ++nf) acc[mf][nf] = (f32x4){0.f, 0.f, 0.f, 0.f};

    // staging geometry: chunk c = p*256 + w*64 + lane; row=c>>2, colchunk=c&3
    const int c0r[2] = { (0 * 256 + w * 64 + lane) >> 2, (1 * 256 + w * 64 + lane) >> 2 };
    const int c0c[2] = { ((0 * 256 + w * 64 + lane) & 3) * 8, ((1 * 256 + w * 64 + lane) & 3) * 8 };
    const int lbase[2] = { (0 * 256 + w * 64) * 8, (1 * 256 + w * 64) * 8 };  // shorts

    const short* Arow0 = A + (size_t)(m0 + c0r[0]) * lda + c0c[0];
    const short* Arow1 = A + (size_t)(m0 + c0r[1]) * lda + c0c[1];
    const short* Brow0 = B + (size_t)(n0 + c0r[0]) * ldb + c0c[0];
    const short* Brow1 = B + (size_t)(n0 + c0r[1]) * ldb + c0c[1];

    for (int kt = 0; kt < nk; ++kt) {
        const int kk0 = kt * 32;
        g2l16(Arow0 + kk0, As + lbase[0]);
        g2l16(Arow1 + kk0, As + lbase[1]);
        g2l16(Brow0 + kk0, Bs + lbase[0]);
        g2l16(Brow1 + kk0, Bs + lbase[1]);
        __syncthreads();   // drains vmcnt(0): tiles resident

        bf16x8 af[4], bf[4];
#pragma unroll
        for (int mf = 0; mf < 4; ++mf)
            af[mf] = *(const bf16x8*)&As[(wr * 64 + mf * 16 + lo) * 32 + g * 8];
#pragma unroll
        for (int nf = 0; nf < 4; ++nf)
            bf[nf] = *(const bf16x8*)&Bs[(wc * 64 + nf * 16 + lo) * 32 + g * 8];
#pragma unroll
        for (int mf = 0; mf < 4; ++mf)
#pragma unroll
            for (int nf = 0; nf < 4; ++nf)
                acc[mf][nf] = __builtin_amdgcn_mfma_f32_16x16x32_bf16(
                    af[mf], bf[nf], acc[mf][nf], 0, 0, 0);
        __syncthreads();   // tile consumed, safe to overwrite
    }

#pragma unroll
    for (int nf = 0; nf < 4; ++nf) {
        const int col = n0 + wc * 64 + nf * 16 + lo;
        float bv = 0.f;
        if constexpr (EPI == 2) bv = bias[col];
#pragma unroll
        for (int mf = 0; mf < 4; ++mf) {
#pragma unroll
            for (int r = 0; r < 4; ++r) {
                const size_t oaddr =
                    (size_t)(m0 + wr * 64 + mf * 16 + g * 4 + r) * ldc + col;
                if constexpr (EPI == 0)
                    ((float*)C)[oaddr] = acc[mf][nf][r] * scale;
                else if constexpr (EPI == 1)
                    ((short*)C)[oaddr] = f2bf(acc[mf][nf][r]);
                else
                    ((float*)C)[oaddr] = acc[mf][nf][r] + bv;
            }
        }
    }
}

// ---- gemm1: S[q][k] = scale * Qb[q][:]·Kb[k][:] ----
__global__ __launch_bounds__(256) void gemm1_kernel(
    const short* __restrict__ Qb, const short* __restrict__ Kb,
    float* __restrict__ S) {
    __shared__ __align__(16) short As[128 * 32];
    __shared__ __align__(16) short Bs[128 * 32];
    const int cb = blockIdx.x >> 8;
    const int t  = blockIdx.x & 255;
    const int qt = t >> 5, ktile = t & 31;
    gemm_bt<0>(Qb + (size_t)cb * LQS * DDIM, DDIM,
               Kb + (size_t)cb * LKS * DDIM, DDIM,
               S + (size_t)cb * ((size_t)LQS * LKS), LKS,
               nullptr, qt * 128, ktile * 128, DDIM / 32, QKSCALE, As, Bs);
}

// ---- gemm2: attedT[d][q] = VT[d][:]·P[q][:]  (P bf16, row stride 8192 shorts) ----
__global__ __launch_bounds__(256) void gemm2_kernel(
    const short* __restrict__ VT, const float* __restrict__ S,
    short* __restrict__ attedT) {
    __shared__ __align__(16) short As[128 * 32];
    __shared__ __align__(16) short Bs[128 * 32];
    const int cb = blockIdx.x >> 6;
    const int t  = blockIdx.x & 63;
    const int dt = t >> 3, qt = t & 7;
    gemm_bt<1>(VT + (size_t)cb * ((size_t)DDIM * LKS), LKS,
               (const short*)(S + (size_t)cb * ((size_t)LQS * LKS)), 2 * LKS,
               attedT + (size_t)cb * ((size_t)DDIM * LQS), LQS,
               nullptr, dt * 128, qt * 128, LKS / 32, 1.f, As, Bs);
}

// ---- merge: out[d][o] = attedT[d][:]·Wb[o][:] + bias[o] ----
__global__ __launch_bounds__(256) void merge_kernel(
    const short* __restrict__ attedT, const short* __restrict__ Wb,
    const float* __restrict__ bias, float* __restrict__ out) {
    __shared__ __align__(16) short As[128 * 32];
    __shared__ __align__(16) short Bs[128 * 32];
    const int cb = blockIdx.x >> 6;
    const int t  = blockIdx.x & 63;
    const int dt = t >> 3, ot = t & 7;
    gemm_bt<2>(attedT + (size_t)cb * ((size_t)DDIM * LQS), LQS,
               Wb, DDIM,
               out + (size_t)cb * ((size_t)DDIM * LQS), DDIM,
               bias, dt * 128, ot * 128, DDIM / 32, 1.f, As, Bs);
}

// ---- softmax: one block per q-row; masked; writes normalized P bf16 in-place
__global__ __launch_bounds__(256) void softmax_kernel(
    float* __restrict__ S, const void* __restrict__ mask,
    const int* __restrict__ flags, int c0) {
    __shared__ float red[4];
    const int tid = threadIdx.x, w = tid >> 6, lane = tid & 63;
    const int cb = blockIdx.x >> 10;
    const int q  = blockIdx.x & 1023;
    const int mflag = flags[0];

    float* Srow = S + ((size_t)cb * LQS + q) * LKS;
    const size_t roff = ((size_t)(c0 + cb) * LQS + q) * LKS;

    float sc[16];
#pragma unroll
    for (int j = 0; j < 4; ++j) {
        const f32x4 sv = ((const f32x4*)Srow)[j * 256 + tid];
        int m0, m1, m2, m3;
        if (mflag) {
            const int4 mv = ((const int4*)((const int*)mask + roff))[j * 256 + tid];
            m0 = mv.x; m1 = mv.y; m2 = mv.z; m3 = mv.w;
        } else {
            const uchar4 mv = ((const uchar4*)((const unsigned char*)mask + roff))[j * 256 + tid];
            m0 = mv.x; m1 = mv.y; m2 = mv.z; m3 = mv.w;
        }
        sc[j * 4 + 0] = m0 ? NEGINF : sv[0];
        sc[j * 4 + 1] = m1 ? NEGINF : sv[1];
        sc[j * 4 + 2] = m2 ? NEGINF : sv[2];
        sc[j * 4 + 3] = m3 ? NEGINF : sv[3];
    }

    float lm = -INFINITY;
#pragma unroll
    for (int i = 0; i < 16; ++i) lm = fmaxf(lm, sc[i]);
#pragma unroll
    for (int off = 1; off < 64; off <<= 1) lm = fmaxf(lm, __shfl_xor(lm, off));
    if (lane == 0) red[w] = lm;
    __syncthreads();
    const float m = fmaxf(fmaxf(red[0], red[1]), fmaxf(red[2], red[3]));

    float p[16], ls = 0.f;
#pragma unroll
    for (int i = 0; i < 16; ++i) { p[i] = __expf(sc[i] - m); ls += p[i]; }
#pragma unroll
    for (int off = 1; off < 64; off <<= 1) ls += __shfl_xor(ls, off);
    __syncthreads();
    if (lane == 0) red[w] = ls;
    __syncthreads();
    const float inv = 1.f / (red[0] + red[1] + red[2] + red[3]);

    short* Prow = (short*)Srow;
#pragma unroll
    for (int j = 0; j < 4; ++j) {
        bf16x4v pv;
#pragma unroll
        for (int i = 0; i < 4; ++i) pv[i] = f2bf(p[j * 4 + i] * inv);
        ((bf16x4v*)Prow)[j * 256 + tid] = pv;
    }
}

extern "C" void kernel_launch(void* const* d_in, const int* in_sizes, int n_in,
                              void* d_out, int out_size, void* d_ws, size_t ws_size,
                              hipStream_t stream) {
    // setup_inputs order: v, k, q, mask, W_merge, b_merge (fp32; mask i32/u8)
    const float* v    = (const float*)d_in[0];
    const float* k    = (const float*)d_in[1];
    const float* q    = (const float*)d_in[2];
    const void*  mask = d_in[3];
    const float* Wm   = (const float*)d_in[4];
    const float* bias = (const float*)d_in[5];
    float* out = (float*)d_out;

    // layout: flags 4KiB | Wb 2MiB | chunk arena nb*36MiB
    //   chunk: S nb*16MiB | VT nb*8MiB | attedT nb*2MiB | Qb nb*2MiB | Kb nb*8MiB
    const size_t base = 4096 + (2ull << 20);
    int nb = 0;
    for (int cand = 8; cand >= 1; cand >>= 1)
        if (base + (size_t)cand * (36ull << 20) <= ws_size) { nb = cand; break; }
    if (!nb) return;

    int*   flags = (int*)d_ws;
    short* Wb    = (short*)((char*)d_ws + 4096);
    char*  ar    = (char*)d_ws + base;
    float* Sbuf   = (float*)ar;
    short* VTbuf  = (short*)(ar + ((size_t)nb << 24));
    short* attedT = (short*)(ar + ((size_t)nb << 24) + ((size_t)nb << 23));
    short* Qb     = (short*)(ar + ((size_t)nb << 24) + ((size_t)nb << 23) + ((size_t)nb << 21));
    short* Kb     = (short*)(ar + ((size_t)nb << 24) + ((size_t)nb << 23) + 2 * ((size_t)nb << 21));

    hipLaunchKernelGGL(detect_kernel, dim3(1), dim3(64), 0, stream,
                       (const unsigned char*)mask, flags);
    hipLaunchKernelGGL(cvt_kernel, dim3(512), dim3(256), 0, stream,
                       Wm, Wb, (int)(DDIM * DDIM / 8));

    for (int c0 = 0; c0 < NBATCH; c0 += nb) {
        const float* vc = v + (size_t)c0 * LKS * DDIM;
        const float* kc = k + (size_t)c0 * LKS * DDIM;
        const float* qc = q + (size_t)c0 * LQS * DDIM;
        float*       oc = out + (size_t)c0 * DDIM * LQS;

        hipLaunchKernelGGL(cvt_kernel, dim3(1024), dim3(256), 0, stream,
                           qc, Qb, nb * (LQS * DDIM / 8));
        hipLaunchKernelGGL(cvt_kernel, dim3(2048), dim3(256), 0, stream,
                           kc, Kb, nb * (LKS * DDIM / 8));
        hipLaunchKernelGGL(transv_kernel, dim3(nb * 1024), dim3(256), 0, stream,
                           vc, VTbuf);
        hipLaunchKernelGGL(gemm1_kernel, dim3(nb * 256), dim3(256), 0, stream,
                           Qb, Kb, Sbuf);
        hipLaunchKernelGGL(softmax_kernel, dim3(nb * 1024), dim3(256), 0, stream,
                           Sbuf, mask, flags, c0);
        hipLaunchKernelGGL(gemm2_kernel, dim3(nb * 64), dim3(256), 0, stream,
                           VTbuf, Sbuf, attedT);
        hipLaunchKernelGGL(merge_kernel, dim3(nb * 64), dim3(256), 0, stream,
                           attedT, Wb, bias, oc);
    }
}

// Round 7
// 382.307 us; speedup vs baseline: 6.1592x; 1.1445x over previous
//
#include <hip/hip_runtime.h>
#include <stdint.h>

typedef __attribute__((ext_vector_type(4))) float f32x4;
typedef __attribute__((ext_vector_type(8))) short bf16x8;
typedef __attribute__((ext_vector_type(4))) short bf16x4v;
typedef __attribute__((ext_vector_type(4))) unsigned int u32x4;

#define NBATCH 8
#define LQS    1024
#define LKS    4096
#define DDIM   1024
#define QKSCALE 0.03125f
#define NEGINF -1000000000.0f
#define BK 64

__device__ __forceinline__ short f2bf(float x) {  // round-to-nearest-even
    unsigned u = __builtin_bit_cast(unsigned, x);
    unsigned r = (u + 0x7fffu + ((u >> 16) & 1u)) >> 16;
    return (short)r;
}

__device__ __forceinline__ bf16x8 cvt8(const float* f) {
    const u32x4* u = (const u32x4*)f;
    const u32x4 a = u[0], b = u[1];
    union { unsigned w[4]; bf16x8 v; } c;
    c.w[0] = __builtin_amdgcn_perm(a[1], a[0], 0x07060302u);
    c.w[1] = __builtin_amdgcn_perm(a[3], a[2], 0x07060302u);
    c.w[2] = __builtin_amdgcn_perm(b[1], b[0], 0x07060302u);
    c.w[3] = __builtin_amdgcn_perm(b[3], b[2], 0x07060302u);
    return c.v;
}

__device__ __forceinline__ void g2l16(const void* g, void* lds) {
    __builtin_amdgcn_global_load_lds(
        (const __attribute__((address_space(1))) unsigned int*)g,
        (__attribute__((address_space(3))) unsigned int*)lds,
        16, 0, 0);
}

// ---- mask dtype detection ----
__global__ void detect_kernel(const unsigned char* __restrict__ mb,
                              int* __restrict__ flags) {
    if (threadIdx.x != 0 || blockIdx.x != 0) return;
    int is_i32 = 1;
    for (int i = 0; i < 256; ++i) {
        if ((i & 3) != 0 && mb[i] != 0) { is_i32 = 0; break; }
    }
    flags[0] = is_i32;
}

// ---- bulk fp32 -> bf16 ----
__global__ __launch_bounds__(256) void cvt_kernel(
    const float* __restrict__ src, short* __restrict__ dst, int n8) {
    const int stride = gridDim.x * 256;
    for (int i = blockIdx.x * 256 + threadIdx.x; i < n8; i += stride)
        ((bf16x8*)dst)[i] = cvt8(src + (size_t)i * 8);
}

// ---- transpose V[k][d] fp32 -> VT[d][k] bf16, 64x64 tiles ----
__global__ __launch_bounds__(256) void transv_kernel(
    const float* __restrict__ V, short* __restrict__ VT) {
    __shared__ short LDSt[64 * 72];
    const int tid = threadIdx.x;
    const int cb  = blockIdx.x >> 10;
    const int t   = blockIdx.x & 1023;
    const int kt  = t >> 4, dt = t & 15;
    const int k0  = kt * 64, d0 = dt * 64;
    const float* Vb  = V  + (size_t)cb * LKS * DDIM;
    short*       VTb = VT + (size_t)cb * ((size_t)DDIM * LKS);

    const int r  = tid >> 4;
    const int cp = (tid & 15) * 4;
#pragma unroll
    for (int rr = 0; rr < 4; ++rr) {
        const int row = rr * 16 + r;
        const f32x4 v = *(const f32x4*)(Vb + (size_t)(k0 + row) * DDIM + d0 + cp);
#pragma unroll
        for (int i = 0; i < 4; ++i) LDSt[(cp + i) * 72 + row] = f2bf(v[i]);
    }
    __syncthreads();
    const int dr = tid >> 2;
    const int kq = (tid & 3) * 16;
    const bf16x8 o0 = *(const bf16x8*)&LDSt[dr * 72 + kq];
    const bf16x8 o1 = *(const bf16x8*)&LDSt[dr * 72 + kq + 8];
    short* dst = VTb + (size_t)(d0 + dr) * LKS + k0 + kq;
    *(bf16x8*)dst       = o0;
    *(bf16x8*)(dst + 8) = o1;
}

// ============ 256x256 8-phase GEMM-BT (T2+T3+T4+T5 port) ============
// C[M][N] = A[M][K]*B[N][K]^T, bf16 in, BK=64, 512thr/8waves (2Mx4N).
// LDS 128KiB: buf b @ b*32768 shorts; A halves @ +0/+8192, B halves @ +16384/+24576.
// Swizzle: 16B chunk index c stored at c^(row&7) (inverse-swz global src, swz read).

__device__ __forceinline__ void stage_half(const short* gbase, int ld,
                                           short* ldshalf, int tid) {
    const int r0 = tid >> 3;
    const int gc = (tid & 7) ^ (r0 & 7);
    const short* s0 = gbase + (size_t)r0 * ld + gc * 8;
    const short* s1 = gbase + (size_t)(r0 + 64) * ld + gc * 8;
    g2l16(s0, ldshalf + (tid & 0x1C0) * 8);
    g2l16(s1, ldshalf + 4096 + (tid & 0x1C0) * 8);
}

__device__ __forceinline__ bf16x8 rdfrag(const short* lds, int base, int r, int c) {
    return *(const bf16x8*)&lds[base + r * 64 + ((c ^ (r & 7)) << 3)];
}

#define MFMA16(d, a, b) d = __builtin_amdgcn_mfma_f32_16x16x32_bf16(a, b, d, 0, 0, 0)

#define PHASE(MF0, STAGE, TAIL)                                             \
    {                                                                       \
        bf16x8 a00 = rdfrag(lds, aBase, (MF0) * 16 + lo, g);                \
        bf16x8 a01 = rdfrag(lds, aBase, (MF0) * 16 + lo, 4 + g);            \
        bf16x8 a10 = rdfrag(lds, aBase, (MF0) * 16 + 16 + lo, g);           \
        bf16x8 a11 = rdfrag(lds, aBase, (MF0) * 16 + 16 + lo, 4 + g);       \
        STAGE;                                                              \
        asm volatile("s_barrier" ::: "memory");                             \
        __builtin_amdgcn_s_setprio(1);                                      \
        _Pragma("unroll")                                                   \
        for (int nf = 0; nf < 4; ++nf) {                                    \
            MFMA16(acc[(MF0)][nf], a00, bfr[nf][0]);                        \
            MFMA16(acc[(MF0)][nf], a01, bfr[nf][1]);                        \
            MFMA16(acc[(MF0) + 1][nf], a10, bfr[nf][0]);                    \
            MFMA16(acc[(MF0) + 1][nf], a11, bfr[nf][1]);                    \
        }                                                                   \
        __builtin_amdgcn_s_setprio(0);                                      \
        TAIL;                                                               \
        asm volatile("s_barrier" ::: "memory");                             \
    }

// EPI: 0 = fp32 store *scale ; 1 = bf16 store ; 2 = fp32 store + bias
template <int EPI>
__device__ __forceinline__ void gemm8p_body(
    const short* __restrict__ A, int lda,
    const short* __restrict__ B, int ldb,
    void* __restrict__ C, int ldc,
    const float* __restrict__ bias,
    int m0, int n0, int NK, float scale, short* lds) {

    const int tid = threadIdx.x;
    const int w = tid >> 6, lane = tid & 63;
    const int lo = lane & 15, g = lane >> 4;
    const int wr = w >> 2, wc = w & 3;

    const short* gA0 = A + (size_t)m0 * lda;
    const short* gA1 = A + (size_t)(m0 + 128) * lda;
    const short* gB0 = B + (size_t)n0 * ldb;
    const short* gB1 = B + (size_t)(n0 + 128) * ldb;

    f32x4 acc[8][4];
#pragma unroll
    for (int mf = 0; mf < 8; ++mf)
#pragma unroll
        for (int nf = 0; nf < 4; ++nf) acc[mf][nf] = (f32x4){0.f, 0.f, 0.f, 0.f};

    // prologue: kt0 full + B halves of kt1
    stage_half(gA0, lda, lds + 0,     tid);
    stage_half(gA1, lda, lds + 8192,  tid);
    stage_half(gB0, ldb, lds + 16384, tid);
    stage_half(gB1, ldb, lds + 24576, tid);
    stage_half(gB0 + BK, ldb, lds + 32768 + 16384, tid);
    stage_half(gB1 + BK, ldb, lds + 32768 + 24576, tid);
    asm volatile("s_waitcnt vmcnt(4)" ::: "memory");   // kt0 resident
    asm volatile("s_barrier" ::: "memory");

    for (int kt = 0; kt < NK; ++kt) {
        const int cb = (kt & 1) << 15;
        const int ob = cb ^ 32768;
        const int aBase = cb + wr * 8192;
        const int bBase = cb + 16384 + (wc >> 1) * 8192;
        const int brow  = (wc & 1) * 64;
        const int kA = (kt + 1) * BK, kB = (kt + 2) * BK;
        const bool doA = (kt + 1) < NK, doB = (kt + 2) < NK;

        bf16x8 bfr[4][2];
#pragma unroll
        for (int nf = 0; nf < 4; ++nf) {
            bfr[nf][0] = rdfrag(lds, bBase, brow + nf * 16 + lo, g);
            bfr[nf][1] = rdfrag(lds, bBase, brow + nf * 16 + lo, 4 + g);
        }
        PHASE(0, if (doA) stage_half(gA0 + kA, lda, lds + ob, tid), )
        PHASE(2, if (doA) stage_half(gA1 + kA, lda, lds + ob + 8192, tid), )
        PHASE(4, if (doB) stage_half(gB0 + kB, ldb, lds + cb + 16384, tid), )
        PHASE(6, if (doB) stage_half(gB1 + kB, ldb, lds + cb + 24576, tid),
                 asm volatile("s_waitcnt vmcnt(4)" ::: "memory"))
    }

#pragma unroll
    for (int nf = 0; nf < 4; ++nf) {
        const int col = n0 + wc * 64 + nf * 16 + lo;
        float bv = 0.f;
        if constexpr (EPI == 2) bv = bias[col];
#pragma unroll
        for (int mf = 0; mf < 8; ++mf) {
#pragma unroll
            for (int rr = 0; rr < 4; ++rr) {
                const size_t oa =
                    (size_t)(m0 + wr * 128 + mf * 16 + g * 4 + rr) * ldc + col;
                if constexpr (EPI == 0)      ((float*)C)[oa] = acc[mf][nf][rr] * scale;
                else if constexpr (EPI == 1) ((short*)C)[oa] = f2bf(acc[mf][nf][rr]);
                else                         ((float*)C)[oa] = acc[mf][nf][rr] + bv;
            }
        }
    }
}

// ---- gemm1: S[q][k] = scale * Qb·Kb^T ; per cb: M=1024, N=4096, K=1024 ----
__global__ __launch_bounds__(512, 2) void gemm1_kernel(
    const short* __restrict__ Qb, const short* __restrict__ Kb,
    float* __restrict__ S) {
    __shared__ __align__(16) short lds[65536];
    const int cb = blockIdx.x >> 6;
    const int t  = blockIdx.x & 63;
    gemm8p_body<0>(Qb + (size_t)cb * LQS * DDIM, DDIM,
                   Kb + (size_t)cb * LKS * DDIM, DDIM,
                   S + (size_t)cb * ((size_t)LQS * LKS), LKS, nullptr,
                   (t >> 4) * 256, (t & 15) * 256, DDIM / BK, QKSCALE, lds);
}

// ---- gemm2: attedT[d][q] = VT·P^T ; per cb: M=1024, N=1024, K=4096 ----
__global__ __launch_bounds__(512, 2) void gemm2_kernel(
    const short* __restrict__ VT, const short* __restrict__ Pd,
    short* __restrict__ attedT) {
    __shared__ __align__(16) short lds[65536];
    const int cb = blockIdx.x >> 4;
    const int t  = blockIdx.x & 15;
    gemm8p_body<1>(VT + (size_t)cb * ((size_t)DDIM * LKS), LKS,
                   Pd + (size_t)cb * ((size_t)LQS * LKS), LKS,
                   attedT + (size_t)cb * ((size_t)DDIM * LQS), LQS, nullptr,
                   (t >> 2) * 256, (t & 3) * 256, LKS / BK, 1.f, lds);
}

// ---- merge: out[(b,d)][o] = attedT·Wb^T + bias ; M=nb*1024, N=1024, K=1024 ----
__global__ __launch_bounds__(512, 2) void merge_kernel(
    const short* __restrict__ attedT, const short* __restrict__ Wb,
    const float* __restrict__ bias, float* __restrict__ out) {
    __shared__ __align__(16) short lds[65536];
    const int mt = blockIdx.x >> 2;
    const int nt = blockIdx.x & 3;
    gemm8p_body<2>(attedT, DDIM, Wb, DDIM, out, DDIM, bias,
                   mt * 256, nt * 256, DDIM / BK, 1.f, lds);
}

// ---- softmax: one block per q-row; reads S fp32, writes DENSE P bf16 ----
__global__ __launch_bounds__(256) void softmax_kernel(
    const float* __restrict__ S, short* __restrict__ Pd,
    const void* __restrict__ mask, const int* __restrict__ flags, int c0) {
    __shared__ float red[4];
    const int tid = threadIdx.x, w = tid >> 6, lane = tid & 63;
    const int cb = blockIdx.x >> 10;
    const int q  = blockIdx.x & 1023;
    const int mflag = flags[0];

    const float* Srow = S + ((size_t)cb * LQS + q) * LKS;
    const size_t roff = ((size_t)(c0 + cb) * LQS + q) * LKS;

    float sc[16];
#pragma unroll
    for (int j = 0; j < 4; ++j) {
        const f32x4 sv = ((const f32x4*)Srow)[j * 256 + tid];
        int m0, m1, m2, m3;
        if (mflag) {
            const int4 mv = ((const int4*)((const int*)mask + roff))[j * 256 + tid];
            m0 = mv.x; m1 = mv.y; m2 = mv.z; m3 = mv.w;
        } else {
            const uchar4 mv = ((const uchar4*)((const unsigned char*)mask + roff))[j * 256 + tid];
            m0 = mv.x; m1 = mv.y; m2 = mv.z; m3 = mv.w;
        }
        sc[j * 4 + 0] = m0 ? NEGINF : sv[0];
        sc[j * 4 + 1] = m1 ? NEGINF : sv[1];
        sc[j * 4 + 2] = m2 ? NEGINF : sv[2];
        sc[j * 4 + 3] = m3 ? NEGINF : sv[3];
    }

    float lm = -INFINITY;
#pragma unroll
    for (int i = 0; i < 16; ++i) lm = fmaxf(lm, sc[i]);
#pragma unroll
    for (int off = 1; off < 64; off <<= 1) lm = fmaxf(lm, __shfl_xor(lm, off));
    if (lane == 0) red[w] = lm;
    __syncthreads();
    const float m = fmaxf(fmaxf(red[0], red[1]), fmaxf(red[2], red[3]));

    float p[16], ls = 0.f;
#pragma unroll
    for (int i = 0; i < 16; ++i) { p[i] = __expf(sc[i] - m); ls += p[i]; }
#pragma unroll
    for (int off = 1; off < 64; off <<= 1) ls += __shfl_xor(ls, off);
    __syncthreads();
    if (lane == 0) red[w] = ls;
    __syncthreads();
    const float inv = 1.f / (red[0] + red[1] + red[2] + red[3]);

    short* Prow = Pd + ((size_t)cb * LQS + q) * LKS;
#pragma unroll
    for (int j = 0; j < 4; ++j) {
        bf16x4v pv;
#pragma unroll
        for (int i = 0; i < 4; ++i) pv[i] = f2bf(p[j * 4 + i] * inv);
        ((bf16x4v*)Prow)[j * 256 + tid] = pv;
    }
}

extern "C" void kernel_launch(void* const* d_in, const int* in_sizes, int n_in,
                              void* d_out, int out_size, void* d_ws, size_t ws_size,
                              hipStream_t stream) {
    // setup_inputs order: v, k, q, mask, W_merge, b_merge (fp32; mask i32/u8)
    const float* v    = (const float*)d_in[0];
    const float* k    = (const float*)d_in[1];
    const float* q    = (const float*)d_in[2];
    const void*  mask = d_in[3];
    const float* Wm   = (const float*)d_in[4];
    const float* bias = (const float*)d_in[5];
    float* out = (float*)d_out;

    // layout: flags 4KiB | Wb 2MiB | chunk arena nb*36MiB
    //   chunk: S nb*16MiB | VT nb*8MiB | attedT nb*2MiB | Qb nb*2MiB | Kb nb*8MiB
    // Pd (dense bf16 P, nb*8MiB) reuses Kb (dead after gemm1).
    const size_t base = 4096 + (2ull << 20);
    int nb = 0;
    for (int cand = 8; cand >= 1; cand >>= 1)
        if (base + (size_t)cand * (36ull << 20) <= ws_size) { nb = cand; break; }
    if (!nb) return;

    int*   flags = (int*)d_ws;
    short* Wb    = (short*)((char*)d_ws + 4096);
    char*  ar    = (char*)d_ws + base;
    float* Sbuf   = (float*)ar;
    short* VTbuf  = (short*)(ar + ((size_t)nb << 24));
    short* attedT = (short*)(ar + ((size_t)nb << 24) + ((size_t)nb << 23));
    short* Qb     = (short*)(ar + ((size_t)nb << 24) + ((size_t)nb << 23) + ((size_t)nb << 21));
    short* Kb     = (short*)(ar + ((size_t)nb << 24) + ((size_t)nb << 23) + 2 * ((size_t)nb << 21));
    short* Pd     = Kb;  // aliased: Kb dead after gemm1, Pd live softmax->gemm2

    hipLaunchKernelGGL(detect_kernel, dim3(1), dim3(64), 0, stream,
                       (const unsigned char*)mask, flags);
    hipLaunchKernelGGL(cvt_kernel, dim3(512), dim3(256), 0, stream,
                       Wm, Wb, (int)(DDIM * DDIM / 8));

    for (int c0 = 0; c0 < NBATCH; c0 += nb) {
        const float* vc = v + (size_t)c0 * LKS * DDIM;
        const float* kc = k + (size_t)c0 * LKS * DDIM;
        const float* qc = q + (size_t)c0 * LQS * DDIM;
        float*       oc = out + (size_t)c0 * DDIM * LQS;

        hipLaunchKernelGGL(cvt_kernel, dim3(1024), dim3(256), 0, stream,
                           qc, Qb, nb * (LQS * DDIM / 8));
        hipLaunchKernelGGL(cvt_kernel, dim3(2048), dim3(256), 0, stream,
                           kc, Kb, nb * (LKS * DDIM / 8));
        hipLaunchKernelGGL(transv_kernel, dim3(nb * 1024), dim3(256), 0, stream,
                           vc, VTbuf);
        hipLaunchKernelGGL(gemm1_kernel, dim3(nb * 64), dim3(512), 0, stream,
                           Qb, Kb, Sbuf);
        hipLaunchKernelGGL(softmax_kernel, dim3(nb * 1024), dim3(256), 0, stream,
                           Sbuf, Pd, mask, flags, c0);
        hipLaunchKernelGGL(gemm2_kernel, dim3(nb * 16), dim3(512), 0, stream,
                           VTbuf, Pd, attedT);
        hipLaunchKernelGGL(merge_kernel, dim3(nb * 4 * 4), dim3(512), 0, stream,
                           attedT, Wb, bias, oc);
    }
}

// Round 10
// 367.086 us; speedup vs baseline: 6.4145x; 1.0415x over previous
//
#include <hip/hip_runtime.h>
#include <stdint.h>

typedef __attribute__((ext_vector_type(4))) float f32x4;
typedef __attribute__((ext_vector_type(8))) short bf16x8;
typedef __attribute__((ext_vector_type(4))) short bf16x4v;
typedef __attribute__((ext_vector_type(4))) unsigned int u32x4;

#define NBATCH 8
#define LQS    1024
#define LKS    4096
#define DDIM   1024
#define QKSCALE 0.03125f
#define NEGINF -1000000000.0f
#define BK 64

__device__ __forceinline__ short f2bf(float x) {  // round-to-nearest-even
    unsigned u = __builtin_bit_cast(unsigned, x);
    unsigned r = (u + 0x7fffu + ((u >> 16) & 1u)) >> 16;
    return (short)r;
}

__device__ __forceinline__ bf16x8 cvt8(const float* f) {
    const u32x4* u = (const u32x4*)f;
    const u32x4 a = u[0], b = u[1];
    union { unsigned w[4]; bf16x8 v; } c;
    c.w[0] = __builtin_amdgcn_perm(a[1], a[0], 0x07060302u);
    c.w[1] = __builtin_amdgcn_perm(a[3], a[2], 0x07060302u);
    c.w[2] = __builtin_amdgcn_perm(b[1], b[0], 0x07060302u);
    c.w[3] = __builtin_amdgcn_perm(b[3], b[2], 0x07060302u);
    return c.v;
}

__device__ __forceinline__ void g2l16(const void* g, void* lds) {
    __builtin_amdgcn_global_load_lds(
        (const __attribute__((address_space(1))) unsigned int*)g,
        (__attribute__((address_space(3))) unsigned int*)lds,
        16, 0, 0);
}

// bijective XCD swizzle (all grids % 8 == 0)
__device__ __forceinline__ int xcd_swz(int bid, int nwg) {
    return (bid & 7) * (nwg >> 3) + (bid >> 3);
}

// ---- mask dtype detection ----
__global__ void detect_kernel(const unsigned char* __restrict__ mb,
                              int* __restrict__ flags) {
    if (threadIdx.x != 0 || blockIdx.x != 0) return;
    int is_i32 = 1;
    for (int i = 0; i < 256; ++i) {
        if ((i & 3) != 0 && mb[i] != 0) { is_i32 = 0; break; }
    }
    flags[0] = is_i32;
}

// ---- bulk fp32 -> bf16 ----
__global__ __launch_bounds__(256) void cvt_kernel(
    const float* __restrict__ src, short* __restrict__ dst, int n8) {
    const int stride = gridDim.x * 256;
    for (int i = blockIdx.x * 256 + threadIdx.x; i < n8; i += stride)
        ((bf16x8*)dst)[i] = cvt8(src + (size_t)i * 8);
}

// ---- add two fp32 partials -> bf16 ----
__global__ __launch_bounds__(256) void add2_kernel(
    const float* __restrict__ p0, const float* __restrict__ p1,
    short* __restrict__ dst, int n8) {
    const int stride = gridDim.x * 256;
    for (int i = blockIdx.x * 256 + threadIdx.x; i < n8; i += stride) {
        const f32x4 a0 = ((const f32x4*)p0)[2 * i];
        const f32x4 a1 = ((const f32x4*)p0)[2 * i + 1];
        const f32x4 b0 = ((const f32x4*)p1)[2 * i];
        const f32x4 b1 = ((const f32x4*)p1)[2 * i + 1];
        bf16x8 r;
#pragma unroll
        for (int j = 0; j < 4; ++j) r[j]     = f2bf(a0[j] + b0[j]);
#pragma unroll
        for (int j = 0; j < 4; ++j) r[4 + j] = f2bf(a1[j] + b1[j]);
        ((bf16x8*)dst)[i] = r;
    }
}

// ---- transpose V[k][d] fp32 -> VT[d][k] bf16, 64x64 tiles ----
__global__ __launch_bounds__(256) void transv_kernel(
    const float* __restrict__ V, short* __restrict__ VT) {
    __shared__ short LDSt[64 * 72];
    const int tid = threadIdx.x;
    const int cb  = blockIdx.x >> 10;
    const int t   = blockIdx.x & 1023;
    const int kt  = t >> 4, dt = t & 15;
    const int k0  = kt * 64, d0 = dt * 64;
    const float* Vb  = V  + (size_t)cb * LKS * DDIM;
    short*       VTb = VT + (size_t)cb * ((size_t)DDIM * LKS);

    const int r  = tid >> 4;
    const int cp = (tid & 15) * 4;
#pragma unroll
    for (int rr = 0; rr < 4; ++rr) {
        const int row = rr * 16 + r;
        const f32x4 v = *(const f32x4*)(Vb + (size_t)(k0 + row) * DDIM + d0 + cp);
#pragma unroll
        for (int i = 0; i < 4; ++i) LDSt[(cp + i) * 72 + row] = f2bf(v[i]);
    }
    __syncthreads();
    const int dr = tid >> 2;
    const int kq = (tid & 3) * 16;
    const bf16x8 o0 = *(const bf16x8*)&LDSt[dr * 72 + kq];
    const bf16x8 o1 = *(const bf16x8*)&LDSt[dr * 72 + kq + 8];
    short* dst = VTb + (size_t)(d0 + dr) * LKS + k0 + kq;
    *(bf16x8*)dst       = o0;
    *(bf16x8*)(dst + 8) = o1;
}

// ============ shared staging / fragment helpers ============
__device__ __forceinline__ void stage_half(const short* gbase, int ld,
                                           short* ldshalf, int tid) {
    const int r0 = tid >> 3;
    const int gc = (tid & 7) ^ (r0 & 7);
    const short* s0 = gbase + (size_t)r0 * ld + gc * 8;
    const short* s1 = gbase + (size_t)(r0 + 64) * ld + gc * 8;
    g2l16(s0, ldshalf + (tid & 0x1C0) * 8);
    g2l16(s1, ldshalf + 4096 + (tid & 0x1C0) * 8);
}

__device__ __forceinline__ bf16x8 rdfrag(const short* lds, int base, int r, int c) {
    return *(const bf16x8*)&lds[base + r * 64 + ((c ^ (r & 7)) << 3)];
}

#define MFMA16(d, a, b) d = __builtin_amdgcn_mfma_f32_16x16x32_bf16(a, b, d, 0, 0, 0)

#define PHASE(MF0, STAGE, TAIL)                                             \
    {                                                                       \
        bf16x8 a00 = rdfrag(lds, aBase, (MF0) * 16 + lo, g);                \
        bf16x8 a01 = rdfrag(lds, aBase, (MF0) * 16 + lo, 4 + g);            \
        bf16x8 a10 = rdfrag(lds, aBase, (MF0) * 16 + 16 + lo, g);          \
        bf16x8 a11 = rdfrag(lds, aBase, (MF0) * 16 + 16 + lo, 4 + g);      \
        STAGE;                                                              \
        asm volatile("s_barrier" ::: "memory");                             \
        __builtin_amdgcn_s_setprio(1);                                      \
        _Pragma("unroll")                                                   \
        for (int nf = 0; nf < 4; ++nf) {                                    \
            MFMA16(acc[(MF0)][nf], a00, bfr[nf][0]);                        \
            MFMA16(acc[(MF0)][nf], a01, bfr[nf][1]);                        \
            MFMA16(acc[(MF0) + 1][nf], a10, bfr[nf][0]);                    \
            MFMA16(acc[(MF0) + 1][nf], a11, bfr[nf][1]);                    \
        }                                                                   \
        __builtin_amdgcn_s_setprio(0);                                      \
        TAIL;                                                               \
        asm volatile("s_barrier" ::: "memory");                             \
    }

// ============ 256x256 8-phase GEMM-BT ============
// RACE FIX (r10): at kt==NK-2, doB==false means B(kt+2) is never issued, so the
// 4 newest outstanding VMEM ops at TAIL are A(NK-1) itself -> vmcnt(4) was a
// no-op and iteration NK-1 could ds_read A while global_load_lds was landing.
// TAIL now drains to vmcnt(0) when doB is false.
template <int EPI>
__device__ __forceinline__ void gemm8p_body(
    const short* __restrict__ A, int lda,
    const short* __restrict__ B, int ldb,
    void* __restrict__ C, int ldc,
    const float* __restrict__ bias,
    int m0, int n0, int NK, float scale, short* lds) {

    const int tid = threadIdx.x;
    const int w = tid >> 6, lane = tid & 63;
    const int lo = lane & 15, g = lane >> 4;
    const int wr = w >> 2, wc = w & 3;

    const short* gA0 = A + (size_t)m0 * lda;
    const short* gA1 = A + (size_t)(m0 + 128) * lda;
    const short* gB0 = B + (size_t)n0 * ldb;
    const short* gB1 = B + (size_t)(n0 + 128) * ldb;

    f32x4 acc[8][4];
#pragma unroll
    for (int mf = 0; mf < 8; ++mf)
#pragma unroll
        for (int nf = 0; nf < 4; ++nf) acc[mf][nf] = (f32x4){0.f, 0.f, 0.f, 0.f};

    stage_half(gA0, lda, lds + 0,     tid);
    stage_half(gA1, lda, lds + 8192,  tid);
    stage_half(gB0, ldb, lds + 16384, tid);
    stage_half(gB1, ldb, lds + 24576, tid);
    stage_half(gB0 + BK, ldb, lds + 32768 + 16384, tid);
    stage_half(gB1 + BK, ldb, lds + 32768 + 24576, tid);
    asm volatile("s_waitcnt vmcnt(4)" ::: "memory");
    asm volatile("s_barrier" ::: "memory");

    for (int kt = 0; kt < NK; ++kt) {
        const int cb = (kt & 1) << 15;
        const int ob = cb ^ 32768;
        const int aBase = cb + wr * 8192;
        const int bBase = cb + 16384 + (wc >> 1) * 8192;
        const int brow  = (wc & 1) * 64;
        const int kA = (kt + 1) * BK, kB = (kt + 2) * BK;
        const bool doA = (kt + 1) < NK, doB = (kt + 2) < NK;

        bf16x8 bfr[4][2];
#pragma unroll
        for (int nf = 0; nf < 4; ++nf) {
            bfr[nf][0] = rdfrag(lds, bBase, brow + nf * 16 + lo, g);
            bfr[nf][1] = rdfrag(lds, bBase, brow + nf * 16 + lo, 4 + g);
        }
        PHASE(0, if (doA) stage_half(gA0 + kA, lda, lds + ob, tid), )
        PHASE(2, if (doA) stage_half(gA1 + kA, lda, lds + ob + 8192, tid), )
        PHASE(4, if (doB) stage_half(gB0 + kB, ldb, lds + cb + 16384, tid), )
        PHASE(6, if (doB) stage_half(gB1 + kB, ldb, lds + cb + 24576, tid),
                 {
                     if (doB) { asm volatile("s_waitcnt vmcnt(4)" ::: "memory"); }
                     else     { asm volatile("s_waitcnt vmcnt(0)" ::: "memory"); }
                 })
    }

#pragma unroll
    for (int nf = 0; nf < 4; ++nf) {
        const int col = n0 + wc * 64 + nf * 16 + lo;
        float bv = 0.f;
        if constexpr (EPI == 2) bv = bias[col];
#pragma unroll
        for (int mf = 0; mf < 8; ++mf) {
#pragma unroll
            for (int rr = 0; rr < 4; ++rr) {
                const size_t oa =
                    (size_t)(m0 + wr * 128 + mf * 16 + g * 4 + rr) * ldc + col;
                if constexpr (EPI == 0)      ((float*)C)[oa] = acc[mf][nf][rr] * scale;
                else if constexpr (EPI == 1) ((short*)C)[oa] = f2bf(acc[mf][nf][rr]);
                else                         ((float*)C)[oa] = acc[mf][nf][rr] + bv;
            }
        }
    }
}

// ---- gemm1: S[q][k] = scale * Qb·Kb^T ; 256x256 tiles, grid nb*64 ----
__global__ __launch_bounds__(512, 2) void gemm1_kernel(
    const short* __restrict__ Qb, const short* __restrict__ Kb,
    float* __restrict__ S) {
    __shared__ __align__(16) short lds[65536];
    const int bid = xcd_swz(blockIdx.x, gridDim.x);
    const int cb = bid >> 6;
    const int t  = bid & 63;
    gemm8p_body<0>(Qb + (size_t)cb * LQS * DDIM, DDIM,
                   Kb + (size_t)cb * LKS * DDIM, DDIM,
                   S + (size_t)cb * ((size_t)LQS * LKS), LKS, nullptr,
                   (t >> 4) * 256, (t & 15) * 256, DDIM / BK, QKSCALE, lds);
}

// ---- gemm2: split-K x2 -> fp32 partials Cpart[s][cb][1024][1024] in Sbuf ----
__global__ __launch_bounds__(512, 2) void gemm2_kernel(
    const short* __restrict__ VT, const short* __restrict__ Pd,
    float* __restrict__ Cpart, int nb) {
    __shared__ __align__(16) short lds[65536];
    const int bid = xcd_swz(blockIdx.x, gridDim.x);
    const int cb = bid >> 5;
    const int t  = (bid >> 1) & 15;
    const int s  = bid & 1;
    float* Cp = Cpart + (size_t)s * nb * (1 << 20) + (size_t)cb * (1 << 20);
    gemm8p_body<0>(VT + (size_t)cb * ((size_t)DDIM * LKS) + s * 2048, LKS,
                   Pd + (size_t)cb * ((size_t)LQS * LKS) + s * 2048, LKS,
                   Cp, LQS, nullptr,
                   (t >> 2) * 256, (t & 3) * 256, 2048 / BK, 1.f, lds);
}

// ---- merge: out[(b,d)][o] = attedT·Wb^T + bias ; 256x256, grid nb*16 ----
__global__ __launch_bounds__(512, 2) void merge_kernel(
    const short* __restrict__ attedT, const short* __restrict__ Wb,
    const float* __restrict__ bias, float* __restrict__ out) {
    __shared__ __align__(16) short lds[65536];
    const int bid = xcd_swz(blockIdx.x, gridDim.x);
    const int mt = bid >> 2;
    const int nt = bid & 3;
    gemm8p_body<2>(attedT, DDIM, Wb, DDIM, out, DDIM, bias,
                   mt * 256, nt * 256, DDIM / BK, 1.f, lds);
}

// ---- softmax: one block per q-row; reads S fp32, writes DENSE P bf16 ----
__global__ __launch_bounds__(256) void softmax_kernel(
    const float* __restrict__ S, short* __restrict__ Pd,
    const void* __restrict__ mask, const int* __restrict__ flags, int c0) {
    __shared__ float red[4];
    const int tid = threadIdx.x, w = tid >> 6, lane = tid & 63;
    const int cb = blockIdx.x >> 10;
    const int q  = blockIdx.x & 1023;
    const int mflag = flags[0];

    const float* Srow = S + ((size_t)cb * LQS + q) * LKS;
    const size_t roff = ((size_t)(c0 + cb) * LQS + q) * LKS;

    float sc[16];
#pragma unroll
    for (int j = 0; j < 4; ++j) {
        const f32x4 sv = ((const f32x4*)Srow)[j * 256 + tid];
        int m0, m1, m2, m3;
        if (mflag) {
            const int4 mv = ((const int4*)((const int*)mask + roff))[j * 256 + tid];
            m0 = mv.x; m1 = mv.y; m2 = mv.z; m3 = mv.w;
        } else {
            const uchar4 mv = ((const uchar4*)((const unsigned char*)mask + roff))[j * 256 + tid];
            m0 = mv.x; m1 = mv.y; m2 = mv.z; m3 = mv.w;
        }
        sc[j * 4 + 0] = m0 ? NEGINF : sv[0];
        sc[j * 4 + 1] = m1 ? NEGINF : sv[1];
        sc[j * 4 + 2] = m2 ? NEGINF : sv[2];
        sc[j * 4 + 3] = m3 ? NEGINF : sv[3];
    }

    float lm = -INFINITY;
#pragma unroll
    for (int i = 0; i < 16; ++i) lm = fmaxf(lm, sc[i]);
#pragma unroll
    for (int off = 1; off < 64; off <<= 1) lm = fmaxf(lm, __shfl_xor(lm, off));
    if (lane == 0) red[w] = lm;
    __syncthreads();
    const float m = fmaxf(fmaxf(red[0], red[1]), fmaxf(red[2], red[3]));

    float p[16], ls = 0.f;
#pragma unroll
    for (int i = 0; i < 16; ++i) { p[i] = __expf(sc[i] - m); ls += p[i]; }
#pragma unroll
    for (int off = 1; off < 64; off <<= 1) ls += __shfl_xor(ls, off);
    __syncthreads();
    if (lane == 0) red[w] = ls;
    __syncthreads();
    const float inv = 1.f / (red[0] + red[1] + red[2] + red[3]);

    short* Prow = Pd + ((size_t)cb * LQS + q) * LKS;
#pragma unroll
    for (int j = 0; j < 4; ++j) {
        bf16x4v pv;
#pragma unroll
        for (int i = 0; i < 4; ++i) pv[i] = f2bf(p[j * 4 + i] * inv);
        ((bf16x4v*)Prow)[j * 256 + tid] = pv;
    }
}

extern "C" void kernel_launch(void* const* d_in, const int* in_sizes, int n_in,
                              void* d_out, int out_size, void* d_ws, size_t ws_size,
                              hipStream_t stream) {
    // setup_inputs order: v, k, q, mask, W_merge, b_merge (fp32; mask i32/u8)
    const float* v    = (const float*)d_in[0];
    const float* k    = (const float*)d_in[1];
    const float* q    = (const float*)d_in[2];
    const void*  mask = d_in[3];
    const float* Wm   = (const float*)d_in[4];
    const float* bias = (const float*)d_in[5];
    float* out = (float*)d_out;

    // layout: flags 4KiB | Wb 2MiB | chunk arena nb*36MiB
    //   chunk: S nb*16MiB | VT nb*8MiB | attedT nb*2MiB | Qb nb*2MiB | Kb nb*8MiB
    // Pd (dense bf16 P, nb*8MiB) reuses Kb (dead after gemm1).
    // Cpart (split-K fp32 partials, 2*nb*4MiB) reuses Sbuf (dead after softmax).
    const size_t base = 4096 + (2ull << 20);
    int nb = 0;
    for (int cand = 8; cand >= 1; cand >>= 1)
        if (base + (size_t)cand * (36ull << 20) <= ws_size) { nb = cand; break; }
    if (!nb) return;

    int*   flags = (int*)d_ws;
    short* Wb    = (short*)((char*)d_ws + 4096);
    char*  ar    = (char*)d_ws + base;
    float* Sbuf   = (float*)ar;
    short* VTbuf  = (short*)(ar + ((size_t)nb << 24));
    short* attedT = (short*)(ar + ((size_t)nb << 24) + ((size_t)nb << 23));
    short* Qb     = (short*)(ar + ((size_t)nb << 24) + ((size_t)nb << 23) + ((size_t)nb << 21));
    short* Kb     = (short*)(ar + ((size_t)nb << 24) + ((size_t)nb << 23) + 2 * ((size_t)nb << 21));
    short* Pd     = Kb;     // aliased: Kb dead after gemm1, Pd live softmax->gemm2
    float* Cpart  = Sbuf;   // aliased: Sbuf dead after softmax

    hipLaunchKernelGGL(detect_kernel, dim3(1), dim3(64), 0, stream,
                       (const unsigned char*)mask, flags);
    hipLaunchKernelGGL(cvt_kernel, dim3(512), dim3(256), 0, stream,
                       Wm, Wb, (int)(DDIM * DDIM / 8));

    for (int c0 = 0; c0 < NBATCH; c0 += nb) {
        const float* vc = v + (size_t)c0 * LKS * DDIM;
        const float* kc = k + (size_t)c0 * LKS * DDIM;
        const float* qc = q + (size_t)c0 * LQS * DDIM;
        float*       oc = out + (size_t)c0 * DDIM * LQS;

        hipLaunchKernelGGL(cvt_kernel, dim3(1024), dim3(256), 0, stream,
                           qc, Qb, nb * (LQS * DDIM / 8));
        hipLaunchKernelGGL(cvt_kernel, dim3(2048), dim3(256), 0, stream,
                           kc, Kb, nb * (LKS * DDIM / 8));
        hipLaunchKernelGGL(transv_kernel, dim3(nb * 1024), dim3(256), 0, stream,
                           vc, VTbuf);
        hipLaunchKernelGGL(gemm1_kernel, dim3(nb * 64), dim3(512), 0, stream,
                           Qb, Kb, Sbuf);
        hipLaunchKernelGGL(softmax_kernel, dim3(nb * 1024), dim3(256), 0, stream,
                           Sbuf, Pd, mask, flags, c0);
        hipLaunchKernelGGL(gemm2_kernel, dim3(nb * 32), dim3(512), 0, stream,
                           VTbuf, Pd, Cpart, nb);
        hipLaunchKernelGGL(add2_kernel, dim3(1024), dim3(256), 0, stream,
                           Cpart, Cpart + (size_t)nb * (1 << 20), attedT,
                           nb * (1 << 17));
        hipLaunchKernelGGL(merge_kernel, dim3(nb * 16), dim3(512), 0, stream,
                           attedT, Wb, bias, oc);
    }
}

// Round 11
// 332.928 us; speedup vs baseline: 7.0727x; 1.1026x over previous
//
#include <hip/hip_runtime.h>
#include <stdint.h>

typedef __attribute__((ext_vector_type(4))) float f32x4;
typedef __attribute__((ext_vector_type(8))) short bf16x8;
typedef __attribute__((ext_vector_type(4))) short bf16x4v;
typedef __attribute__((ext_vector_type(4))) unsigned int u32x4;

#define NBATCH 8
#define LQS    1024
#define LKS    4096
#define DDIM   1024
#define QKSCALE 0.03125f
#define NEGINF -1000000000.0f
#define BK 64

__device__ __forceinline__ short f2bf(float x) {  // round-to-nearest-even
    unsigned u = __builtin_bit_cast(unsigned, x);
    unsigned r = (u + 0x7fffu + ((u >> 16) & 1u)) >> 16;
    return (short)r;
}
__device__ __forceinline__ float bf2f(short s) {
    unsigned u = ((unsigned)(unsigned short)s) << 16;
    return __builtin_bit_cast(float, u);
}

__device__ __forceinline__ bf16x8 cvt8(const float* f) {
    const u32x4* u = (const u32x4*)f;
    const u32x4 a = u[0], b = u[1];
    union { unsigned w[4]; bf16x8 v; } c;
    c.w[0] = __builtin_amdgcn_perm(a[1], a[0], 0x07060302u);
    c.w[1] = __builtin_amdgcn_perm(a[3], a[2], 0x07060302u);
    c.w[2] = __builtin_amdgcn_perm(b[1], b[0], 0x07060302u);
    c.w[3] = __builtin_amdgcn_perm(b[3], b[2], 0x07060302u);
    return c.v;
}

__device__ __forceinline__ void g2l16(const void* g, void* lds) {
    __builtin_amdgcn_global_load_lds(
        (const __attribute__((address_space(1))) unsigned int*)g,
        (__attribute__((address_space(3))) unsigned int*)lds,
        16, 0, 0);
}

// bijective XCD swizzle (all grids % 8 == 0)
__device__ __forceinline__ int xcd_swz(int bid, int nwg) {
    return (bid & 7) * (nwg >> 3) + (bid >> 3);
}

// ---- mask dtype detection ----
__global__ void detect_kernel(const unsigned char* __restrict__ mb,
                              int* __restrict__ flags) {
    if (threadIdx.x != 0 || blockIdx.x != 0) return;
    int is_i32 = 1;
    for (int i = 0; i < 256; ++i) {
        if ((i & 3) != 0 && mb[i] != 0) { is_i32 = 0; break; }
    }
    flags[0] = is_i32;
}

// ---- bulk fp32 -> bf16 ----
__global__ __launch_bounds__(256) void cvt_kernel(
    const float* __restrict__ src, short* __restrict__ dst, int n8) {
    const int stride = gridDim.x * 256;
    for (int i = blockIdx.x * 256 + threadIdx.x; i < n8; i += stride)
        ((bf16x8*)dst)[i] = cvt8(src + (size_t)i * 8);
}

// ---- transpose V[k][d] fp32 -> VT[d][k] bf16, 64x64 tiles ----
__global__ __launch_bounds__(256) void transv_kernel(
    const float* __restrict__ V, short* __restrict__ VT) {
    __shared__ short LDSt[64 * 72];
    const int tid = threadIdx.x;
    const int cb  = blockIdx.x >> 10;
    const int t   = blockIdx.x & 1023;
    const int kt  = t >> 4, dt = t & 15;
    const int k0  = kt * 64, d0 = dt * 64;
    const float* Vb  = V  + (size_t)cb * LKS * DDIM;
    short*       VTb = VT + (size_t)cb * ((size_t)DDIM * LKS);

    const int r  = tid >> 4;
    const int cp = (tid & 15) * 4;
#pragma unroll
    for (int rr = 0; rr < 4; ++rr) {
        const int row = rr * 16 + r;
        const f32x4 v = *(const f32x4*)(Vb + (size_t)(k0 + row) * DDIM + d0 + cp);
#pragma unroll
        for (int i = 0; i < 4; ++i) LDSt[(cp + i) * 72 + row] = f2bf(v[i]);
    }
    __syncthreads();
    const int dr = tid >> 2;
    const int kq = (tid & 3) * 16;
    const bf16x8 o0 = *(const bf16x8*)&LDSt[dr * 72 + kq];
    const bf16x8 o1 = *(const bf16x8*)&LDSt[dr * 72 + kq + 8];
    short* dst = VTb + (size_t)(d0 + dr) * LKS + k0 + kq;
    *(bf16x8*)dst       = o0;
    *(bf16x8*)(dst + 8) = o1;
}

// ============ shared staging / fragment helpers ============
__device__ __forceinline__ void stage_half(const short* gbase, int ld,
                                           short* ldshalf, int tid) {
    const int r0 = tid >> 3;
    const int gc = (tid & 7) ^ (r0 & 7);
    const short* s0 = gbase + (size_t)r0 * ld + gc * 8;
    const short* s1 = gbase + (size_t)(r0 + 64) * ld + gc * 8;
    g2l16(s0, ldshalf + (tid & 0x1C0) * 8);
    g2l16(s1, ldshalf + 4096 + (tid & 0x1C0) * 8);
}

__device__ __forceinline__ bf16x8 rdfrag(const short* lds, int base, int r, int c) {
    return *(const bf16x8*)&lds[base + r * 64 + ((c ^ (r & 7)) << 3)];
}

#define MFMA16(d, a, b) d = __builtin_amdgcn_mfma_f32_16x16x32_bf16(a, b, d, 0, 0, 0)

#define PHASE(MF0, STAGE, TAIL)                                             \
    {                                                                       \
        bf16x8 a00 = rdfrag(lds, aBase, (MF0) * 16 + lo, g);                \
        bf16x8 a01 = rdfrag(lds, aBase, (MF0) * 16 + lo, 4 + g);            \
        bf16x8 a10 = rdfrag(lds, aBase, (MF0) * 16 + 16 + lo, g);          \
        bf16x8 a11 = rdfrag(lds, aBase, (MF0) * 16 + 16 + lo, 4 + g);      \
        STAGE;                                                              \
        asm volatile("s_barrier" ::: "memory");                             \
        __builtin_amdgcn_s_setprio(1);                                      \
        _Pragma("unroll")                                                   \
        for (int nf = 0; nf < 4; ++nf) {                                    \
            MFMA16(acc[(MF0)][nf], a00, bfr[nf][0]);                        \
            MFMA16(acc[(MF0)][nf], a01, bfr[nf][1]);                        \
            MFMA16(acc[(MF0) + 1][nf], a10, bfr[nf][0]);                    \
            MFMA16(acc[(MF0) + 1][nf], a11, bfr[nf][1]);                    \
        }                                                                   \
        __builtin_amdgcn_s_setprio(0);                                      \
        TAIL;                                                               \
        asm volatile("s_barrier" ::: "memory");                             \
    }

// Epilogue store: EPI 0 = fp32*scale ; 1 = bf16 ; 2 = fp32+bias ; 3 = bf16*scale
// ============ 256x256 4-PHASE GEMM-BT (proven; tail-drain fixed in r10) ============
template <int EPI>
__device__ __forceinline__ void gemm8p_body(
    const short* __restrict__ A, int lda,
    const short* __restrict__ B, int ldb,
    void* __restrict__ C, int ldc,
    const float* __restrict__ bias,
    int m0, int n0, int NK, float scale, short* lds) {

    const int tid = threadIdx.x;
    const int w = tid >> 6, lane = tid & 63;
    const int lo = lane & 15, g = lane >> 4;
    const int wr = w >> 2, wc = w & 3;

    const short* gA0 = A + (size_t)m0 * lda;
    const short* gA1 = A + (size_t)(m0 + 128) * lda;
    const short* gB0 = B + (size_t)n0 * ldb;
    const short* gB1 = B + (size_t)(n0 + 128) * ldb;

    f32x4 acc[8][4];
#pragma unroll
    for (int mf = 0; mf < 8; ++mf)
#pragma unroll
        for (int nf = 0; nf < 4; ++nf) acc[mf][nf] = (f32x4){0.f, 0.f, 0.f, 0.f};

    stage_half(gA0, lda, lds + 0,     tid);
    stage_half(gA1, lda, lds + 8192,  tid);
    stage_half(gB0, ldb, lds + 16384, tid);
    stage_half(gB1, ldb, lds + 24576, tid);
    stage_half(gB0 + BK, ldb, lds + 32768 + 16384, tid);
    stage_half(gB1 + BK, ldb, lds + 32768 + 24576, tid);
    asm volatile("s_waitcnt vmcnt(4)" ::: "memory");
    asm volatile("s_barrier" ::: "memory");

    for (int kt = 0; kt < NK; ++kt) {
        const int cb = (kt & 1) << 15;
        const int ob = cb ^ 32768;
        const int aBase = cb + wr * 8192;
        const int bBase = cb + 16384 + (wc >> 1) * 8192;
        const int brow  = (wc & 1) * 64;
        const int kA = (kt + 1) * BK, kB = (kt + 2) * BK;
        const bool doA = (kt + 1) < NK, doB = (kt + 2) < NK;

        bf16x8 bfr[4][2];
#pragma unroll
        for (int nf = 0; nf < 4; ++nf) {
            bfr[nf][0] = rdfrag(lds, bBase, brow + nf * 16 + lo, g);
            bfr[nf][1] = rdfrag(lds, bBase, brow + nf * 16 + lo, 4 + g);
        }
        PHASE(0, if (doA) stage_half(gA0 + kA, lda, lds + ob, tid), )
        PHASE(2, if (doA) stage_half(gA1 + kA, lda, lds + ob + 8192, tid), )
        PHASE(4, if (doB) stage_half(gB0 + kB, ldb, lds + cb + 16384, tid), )
        PHASE(6, if (doB) stage_half(gB1 + kB, ldb, lds + cb + 24576, tid),
                 {
                     if (doB) { asm volatile("s_waitcnt vmcnt(4)" ::: "memory"); }
                     else     { asm volatile("s_waitcnt vmcnt(0)" ::: "memory"); }
                 })
    }

#pragma unroll
    for (int nf = 0; nf < 4; ++nf) {
        const int col = n0 + wc * 64 + nf * 16 + lo;
        float bv = 0.f;
        if constexpr (EPI == 2) bv = bias[col];
#pragma unroll
        for (int mf = 0; mf < 8; ++mf) {
#pragma unroll
            for (int rr = 0; rr < 4; ++rr) {
                const size_t oa =
                    (size_t)(m0 + wr * 128 + mf * 16 + g * 4 + rr) * ldc + col;
                if constexpr (EPI == 0)      ((float*)C)[oa] = acc[mf][nf][rr] * scale;
                else if constexpr (EPI == 1) ((short*)C)[oa] = f2bf(acc[mf][nf][rr]);
                else if constexpr (EPI == 2) ((float*)C)[oa] = acc[mf][nf][rr] + bv;
                else                         ((short*)C)[oa] = f2bf(acc[mf][nf][rr] * scale);
            }
        }
    }
}

// ============ 256x128 2-PHASE variant, tail-drain FIXED ============
// 8 waves as 4M x 2N, per-wave 64x64 (acc[4][4]). LDS 96KiB (buf stride 24576):
// A half0 @0, A half1 @8192, B @16384. Per kt: ph0 stages A(kt+1) [4 ops],
// ph1 stages B(kt+2) [2 ops]; steady vmcnt(2) leaves only B(kt+2);
// at kt==NK-2 (doB false) drain vmcnt(0) so A(NK-1) is resident (r10 fix).
template <int EPI>
__device__ __forceinline__ void gemm8p_n128(
    const short* __restrict__ A, int lda,
    const short* __restrict__ B, int ldb,
    void* __restrict__ C, int ldc,
    const float* __restrict__ bias,
    int m0, int n0, int NK, float scale, short* lds) {

    const int tid = threadIdx.x;
    const int w = tid >> 6, lane = tid & 63;
    const int lo = lane & 15, g = lane >> 4;
    const int wr = w >> 1, wc = w & 1;

    const short* gA0 = A + (size_t)m0 * lda;
    const short* gA1 = A + (size_t)(m0 + 128) * lda;
    const short* gB0 = B + (size_t)n0 * ldb;

    f32x4 acc[4][4];
#pragma unroll
    for (int mf = 0; mf < 4; ++mf)
#pragma unroll
        for (int nf = 0; nf < 4; ++nf) acc[mf][nf] = (f32x4){0.f, 0.f, 0.f, 0.f};

    stage_half(gA0, lda, lds + 0,    tid);
    stage_half(gA1, lda, lds + 8192, tid);
    stage_half(gB0, ldb, lds + 16384, tid);
    stage_half(gB0 + BK, ldb, lds + 24576 + 16384, tid);
    asm volatile("s_waitcnt vmcnt(2)" ::: "memory");
    asm volatile("s_barrier" ::: "memory");

    for (int kt = 0; kt < NK; ++kt) {
        const int cbuf = (kt & 1) * 24576;
        const int obuf = cbuf ^ 24576;
        const int aBase = cbuf + (wr >> 1) * 8192 + (wr & 1) * 4096;
        const int bBase = cbuf + 16384 + wc * 4096;
        const int kA = (kt + 1) * BK, kB = (kt + 2) * BK;
        const bool doA = (kt + 1) < NK, doB = (kt + 2) < NK;

        bf16x8 bfr[4][2];
#pragma unroll
        for (int nf = 0; nf < 4; ++nf) {
            bfr[nf][0] = rdfrag(lds, bBase, nf * 16 + lo, g);
            bfr[nf][1] = rdfrag(lds, bBase, nf * 16 + lo, 4 + g);
        }
        PHASE(0, {
            if (doA) {
                stage_half(gA0 + kA, lda, lds + obuf, tid);
                stage_half(gA1 + kA, lda, lds + obuf + 8192, tid);
            }
        }, )
        PHASE(2, {
            if (doB) stage_half(gB0 + kB, ldb, lds + cbuf + 16384, tid);
        }, {
            if (doB) { asm volatile("s_waitcnt vmcnt(2)" ::: "memory"); }
            else     { asm volatile("s_waitcnt vmcnt(0)" ::: "memory"); }
        })
    }

#pragma unroll
    for (int nf = 0; nf < 4; ++nf) {
        const int col = n0 + wc * 64 + nf * 16 + lo;
        float bv = 0.f;
        if constexpr (EPI == 2) bv = bias[col];
#pragma unroll
        for (int mf = 0; mf < 4; ++mf) {
#pragma unroll
            for (int rr = 0; rr < 4; ++rr) {
                const size_t oa =
                    (size_t)(m0 + wr * 64 + mf * 16 + g * 4 + rr) * ldc + col;
                if constexpr (EPI == 0)      ((float*)C)[oa] = acc[mf][nf][rr] * scale;
                else if constexpr (EPI == 1) ((short*)C)[oa] = f2bf(acc[mf][nf][rr]);
                else if constexpr (EPI == 2) ((float*)C)[oa] = acc[mf][nf][rr] + bv;
                else                         ((short*)C)[oa] = f2bf(acc[mf][nf][rr] * scale);
            }
        }
    }
}

// ---- gemm1: S[q][k] = bf16(scale * Qb·Kb^T) ; 256x256 tiles, grid nb*64 ----
__global__ __launch_bounds__(512, 2) void gemm1_kernel(
    const short* __restrict__ Qb, const short* __restrict__ Kb,
    short* __restrict__ Sb) {
    __shared__ __align__(16) short lds[65536];
    const int bid = xcd_swz(blockIdx.x, gridDim.x);
    const int cb = bid >> 6;
    const int t  = bid & 63;
    gemm8p_body<3>(Qb + (size_t)cb * LQS * DDIM, DDIM,
                   Kb + (size_t)cb * LKS * DDIM, DDIM,
                   Sb + (size_t)cb * ((size_t)LQS * LKS), LKS, nullptr,
                   (t >> 4) * 256, (t & 15) * 256, DDIM / BK, QKSCALE, lds);
}

// ---- gemm2: attedT[d][q] = VT·P^T ; 256x128 tiles, grid nb*32 (full chip) ----
__global__ __launch_bounds__(512, 2) void gemm2_kernel(
    const short* __restrict__ VT, const short* __restrict__ Pd,
    short* __restrict__ attedT) {
    __shared__ __align__(16) short lds[49152];
    const int bid = xcd_swz(blockIdx.x, gridDim.x);
    const int cb = bid >> 5;
    const int t  = bid & 31;
    gemm8p_n128<1>(VT + (size_t)cb * ((size_t)DDIM * LKS), LKS,
                   Pd + (size_t)cb * ((size_t)LQS * LKS), LKS,
                   attedT + (size_t)cb * ((size_t)DDIM * LQS), LQS, nullptr,
                   (t >> 3) * 256, (t & 7) * 128, LKS / BK, 1.f, lds);
}

// ---- merge: out[(b,d)][o] = attedT·Wb^T + bias ; 256x128, grid nb*32 ----
__global__ __launch_bounds__(512, 2) void merge_kernel(
    const short* __restrict__ attedT, const short* __restrict__ Wb,
    const float* __restrict__ bias, float* __restrict__ out) {
    __shared__ __align__(16) short lds[49152];
    const int bid = xcd_swz(blockIdx.x, gridDim.x);
    const int mt = bid >> 3;
    const int nt = bid & 7;
    gemm8p_n128<2>(attedT, DDIM, Wb, DDIM, out, DDIM, bias,
                   mt * 256, nt * 128, DDIM / BK, 1.f, lds);
}

// ---- softmax: one block per q-row; reads bf16 S, writes DENSE P bf16 ----
__global__ __launch_bounds__(256) void softmax_kernel(
    const short* __restrict__ Sb, short* __restrict__ Pd,
    const void* __restrict__ mask, const int* __restrict__ flags, int c0) {
    __shared__ float red[4];
    const int tid = threadIdx.x, w = tid >> 6, lane = tid & 63;
    const int cb = blockIdx.x >> 10;
    const int q  = blockIdx.x & 1023;
    const int mflag = flags[0];

    const short* Srow = Sb + ((size_t)cb * LQS + q) * LKS;
    const size_t roff = ((size_t)(c0 + cb) * LQS + q) * LKS;
    const size_t m4   = roff >> 2;   // int4 / uchar4 base index

    float sc[16];
#pragma unroll
    for (int j = 0; j < 2; ++j) {
        const int i8 = j * 256 + tid;
        const bf16x8 sv = ((const bf16x8*)Srow)[i8];
        int mm[8];
        if (mflag) {
            const int4 a = ((const int4*)mask)[m4 + 2 * i8];
            const int4 b = ((const int4*)mask)[m4 + 2 * i8 + 1];
            mm[0] = a.x; mm[1] = a.y; mm[2] = a.z; mm[3] = a.w;
            mm[4] = b.x; mm[5] = b.y; mm[6] = b.z; mm[7] = b.w;
        } else {
            const uchar4 a = ((const uchar4*)mask)[m4 + 2 * i8];
            const uchar4 b = ((const uchar4*)mask)[m4 + 2 * i8 + 1];
            mm[0] = a.x; mm[1] = a.y; mm[2] = a.z; mm[3] = a.w;
            mm[4] = b.x; mm[5] = b.y; mm[6] = b.z; mm[7] = b.w;
        }
#pragma unroll
        for (int i = 0; i < 8; ++i)
            sc[j * 8 + i] = mm[i] ? NEGINF : bf2f(sv[i]);
    }

    float lm = -INFINITY;
#pragma unroll
    for (int i = 0; i < 16; ++i) lm = fmaxf(lm, sc[i]);
#pragma unroll
    for (int off = 1; off < 64; off <<= 1) lm = fmaxf(lm, __shfl_xor(lm, off));
    if (lane == 0) red[w] = lm;
    __syncthreads();
    const float m = fmaxf(fmaxf(red[0], red[1]), fmaxf(red[2], red[3]));

    float p[16], ls = 0.f;
#pragma unroll
    for (int i = 0; i < 16; ++i) { p[i] = __expf(sc[i] - m); ls += p[i]; }
#pragma unroll
    for (int off = 1; off < 64; off <<= 1) ls += __shfl_xor(ls, off);
    __syncthreads();
    if (lane == 0) red[w] = ls;
    __syncthreads();
    const float inv = 1.f / (red[0] + red[1] + red[2] + red[3]);

    short* Prow = Pd + ((size_t)cb * LQS + q) * LKS;
#pragma unroll
    for (int j = 0; j < 2; ++j) {
        bf16x8 pv;
#pragma unroll
        for (int i = 0; i < 8; ++i) pv[i] = f2bf(p[j * 8 + i] * inv);
        ((bf16x8*)Prow)[j * 256 + tid] = pv;
    }
}

extern "C" void kernel_launch(void* const* d_in, const int* in_sizes, int n_in,
                              void* d_out, int out_size, void* d_ws, size_t ws_size,
                              hipStream_t stream) {
    // setup_inputs order: v, k, q, mask, W_merge, b_merge (fp32; mask i32/u8)
    const float* v    = (const float*)d_in[0];
    const float* k    = (const float*)d_in[1];
    const float* q    = (const float*)d_in[2];
    const void*  mask = d_in[3];
    const float* Wm   = (const float*)d_in[4];
    const float* bias = (const float*)d_in[5];
    float* out = (float*)d_out;

    // layout: flags 4KiB | Wb 2MiB | chunk arena nb*36MiB
    //   chunk: S region nb*16MiB (bf16 S uses first nb*8MiB) | VT nb*8MiB |
    //          attedT nb*2MiB | Qb nb*2MiB | Kb nb*8MiB
    // Pd (dense bf16 P, nb*8MiB) reuses Kb (dead after gemm1).
    const size_t base = 4096 + (2ull << 20);
    int nb = 0;
    for (int cand = 8; cand >= 1; cand >>= 1)
        if (base + (size_t)cand * (36ull << 20) <= ws_size) { nb = cand; break; }
    if (!nb) return;

    int*   flags = (int*)d_ws;
    short* Wb    = (short*)((char*)d_ws + 4096);
    char*  ar    = (char*)d_ws + base;
    short* Sb     = (short*)ar;
    short* VTbuf  = (short*)(ar + ((size_t)nb << 24));
    short* attedT = (short*)(ar + ((size_t)nb << 24) + ((size_t)nb << 23));
    short* Qb     = (short*)(ar + ((size_t)nb << 24) + ((size_t)nb << 23) + ((size_t)nb << 21));
    short* Kb     = (short*)(ar + ((size_t)nb << 24) + ((size_t)nb << 23) + 2 * ((size_t)nb << 21));
    short* Pd     = Kb;     // aliased: Kb dead after gemm1, Pd live softmax->gemm2

    hipLaunchKernelGGL(detect_kernel, dim3(1), dim3(64), 0, stream,
                       (const unsigned char*)mask, flags);
    hipLaunchKernelGGL(cvt_kernel, dim3(512), dim3(256), 0, stream,
                       Wm, Wb, (int)(DDIM * DDIM / 8));

    for (int c0 = 0; c0 < NBATCH; c0 += nb) {
        const float* vc = v + (size_t)c0 * LKS * DDIM;
        const float* kc = k + (size_t)c0 * LKS * DDIM;
        const float* qc = q + (size_t)c0 * LQS * DDIM;
        float*       oc = out + (size_t)c0 * DDIM * LQS;

        hipLaunchKernelGGL(cvt_kernel, dim3(1024), dim3(256), 0, stream,
                           qc, Qb, nb * (LQS * DDIM / 8));
        hipLaunchKernelGGL(cvt_kernel, dim3(2048), dim3(256), 0, stream,
                           kc, Kb, nb * (LKS * DDIM / 8));
        hipLaunchKernelGGL(transv_kernel, dim3(nb * 1024), dim3(256), 0, stream,
                           vc, VTbuf);
        hipLaunchKernelGGL(gemm1_kernel, dim3(nb * 64), dim3(512), 0, stream,
                           Qb, Kb, Sb);
        hipLaunchKernelGGL(softmax_kernel, dim3(nb * 1024), dim3(256), 0, stream,
                           Sb, Pd, mask, flags, c0);
        hipLaunchKernelGGL(gemm2_kernel, dim3(nb * 32), dim3(512), 0, stream,
                           VTbuf, Pd, attedT);
        hipLaunchKernelGGL(merge_kernel, dim3(nb * 32), dim3(512), 0, stream,
                           attedT, Wb, bias, oc);
    }
}

// Round 12
// 322.466 us; speedup vs baseline: 7.3021x; 1.0324x over previous
//
#include <hip/hip_runtime.h>
#include <stdint.h>

typedef __attribute__((ext_vector_type(4))) float f32x4;
typedef __attribute__((ext_vector_type(8))) short bf16x8;
typedef __attribute__((ext_vector_type(4))) short bf16x4v;
typedef __attribute__((ext_vector_type(4))) unsigned int u32x4;

#define NBATCH 8
#define LQS    1024
#define LKS    4096
#define DDIM   1024
#define QKSCALE 0.03125f
#define NEGINF -1000000000.0f
#define BK 64

__device__ __forceinline__ short f2bf(float x) {  // round-to-nearest-even
    unsigned u = __builtin_bit_cast(unsigned, x);
    unsigned r = (u + 0x7fffu + ((u >> 16) & 1u)) >> 16;
    return (short)r;
}
__device__ __forceinline__ float bf2f(short s) {
    unsigned u = ((unsigned)(unsigned short)s) << 16;
    return __builtin_bit_cast(float, u);
}

__device__ __forceinline__ bf16x8 cvt8(const float* f) {
    const u32x4* u = (const u32x4*)f;
    const u32x4 a = u[0], b = u[1];
    union { unsigned w[4]; bf16x8 v; } c;
    c.w[0] = __builtin_amdgcn_perm(a[1], a[0], 0x07060302u);
    c.w[1] = __builtin_amdgcn_perm(a[3], a[2], 0x07060302u);
    c.w[2] = __builtin_amdgcn_perm(b[1], b[0], 0x07060302u);
    c.w[3] = __builtin_amdgcn_perm(b[3], b[2], 0x07060302u);
    return c.v;
}

__device__ __forceinline__ void g2l16(const void* g, void* lds) {
    __builtin_amdgcn_global_load_lds(
        (const __attribute__((address_space(1))) unsigned int*)g,
        (__attribute__((address_space(3))) unsigned int*)lds,
        16, 0, 0);
}

// bijective XCD swizzle (all grids % 8 == 0)
__device__ __forceinline__ int xcd_swz(int bid, int nwg) {
    return (bid & 7) * (nwg >> 3) + (bid >> 3);
}

// ---- mask dtype detection ----
__global__ void detect_kernel(const unsigned char* __restrict__ mb,
                              int* __restrict__ flags) {
    if (threadIdx.x != 0 || blockIdx.x != 0) return;
    int is_i32 = 1;
    for (int i = 0; i < 256; ++i) {
        if ((i & 3) != 0 && mb[i] != 0) { is_i32 = 0; break; }
    }
    flags[0] = is_i32;
}

// ---- bulk fp32 -> bf16 ----
__global__ __launch_bounds__(256) void cvt_kernel(
    const float* __restrict__ src, short* __restrict__ dst, int n8) {
    const int stride = gridDim.x * 256;
    for (int i = blockIdx.x * 256 + threadIdx.x; i < n8; i += stride)
        ((bf16x8*)dst)[i] = cvt8(src + (size_t)i * 8);
}

// ---- transpose V[k][d] fp32 -> VT[d][k] bf16, 64x64 tiles ----
__global__ __launch_bounds__(256) void transv_kernel(
    const float* __restrict__ V, short* __restrict__ VT) {
    __shared__ short LDSt[64 * 72];
    const int tid = threadIdx.x;
    const int cb  = blockIdx.x >> 10;
    const int t   = blockIdx.x & 1023;
    const int kt  = t >> 4, dt = t & 15;
    const int k0  = kt * 64, d0 = dt * 64;
    const float* Vb  = V  + (size_t)cb * LKS * DDIM;
    short*       VTb = VT + (size_t)cb * ((size_t)DDIM * LKS);

    const int r  = tid >> 4;
    const int cp = (tid & 15) * 4;
#pragma unroll
    for (int rr = 0; rr < 4; ++rr) {
        const int row = rr * 16 + r;
        const f32x4 v = *(const f32x4*)(Vb + (size_t)(k0 + row) * DDIM + d0 + cp);
#pragma unroll
        for (int i = 0; i < 4; ++i) LDSt[(cp + i) * 72 + row] = f2bf(v[i]);
    }
    __syncthreads();
    const int dr = tid >> 2;
    const int kq = (tid & 3) * 16;
    const bf16x8 o0 = *(const bf16x8*)&LDSt[dr * 72 + kq];
    const bf16x8 o1 = *(const bf16x8*)&LDSt[dr * 72 + kq + 8];
    short* dst = VTb + (size_t)(d0 + dr) * LKS + k0 + kq;
    *(bf16x8*)dst       = o0;
    *(bf16x8*)(dst + 8) = o1;
}

// ============ shared staging / fragment helpers ============
__device__ __forceinline__ void stage_half(const short* gbase, int ld,
                                           short* ldshalf, int tid) {
    const int r0 = tid >> 3;
    const int gc = (tid & 7) ^ (r0 & 7);
    const short* s0 = gbase + (size_t)r0 * ld + gc * 8;
    const short* s1 = gbase + (size_t)(r0 + 64) * ld + gc * 8;
    g2l16(s0, ldshalf + (tid & 0x1C0) * 8);
    g2l16(s1, ldshalf + 4096 + (tid & 0x1C0) * 8);
}

__device__ __forceinline__ bf16x8 rdfrag(const short* lds, int base, int r, int c) {
    return *(const bf16x8*)&lds[base + r * 64 + ((c ^ (r & 7)) << 3)];
}

#define MFMA16(d, a, b) d = __builtin_amdgcn_mfma_f32_16x16x32_bf16(a, b, d, 0, 0, 0)

#define PHASE(MF0, STAGE, TAIL)                                             \
    {                                                                       \
        bf16x8 a00 = rdfrag(lds, aBase, (MF0) * 16 + lo, g);                \
        bf16x8 a01 = rdfrag(lds, aBase, (MF0) * 16 + lo, 4 + g);            \
        bf16x8 a10 = rdfrag(lds, aBase, (MF0) * 16 + 16 + lo, g);          \
        bf16x8 a11 = rdfrag(lds, aBase, (MF0) * 16 + 16 + lo, 4 + g);      \
        STAGE;                                                              \
        asm volatile("s_barrier" ::: "memory");                             \
        __builtin_amdgcn_s_setprio(1);                                      \
        _Pragma("unroll")                                                   \
        for (int nf = 0; nf < 4; ++nf) {                                    \
            MFMA16(acc[(MF0)][nf], a00, bfr[nf][0]);                        \
            MFMA16(acc[(MF0)][nf], a01, bfr[nf][1]);                        \
            MFMA16(acc[(MF0) + 1][nf], a10, bfr[nf][0]);                    \
            MFMA16(acc[(MF0) + 1][nf], a11, bfr[nf][1]);                    \
        }                                                                   \
        __builtin_amdgcn_s_setprio(0);                                      \
        TAIL;                                                               \
        asm volatile("s_barrier" ::: "memory");                             \
    }

// Epilogue store: EPI 0 = fp32*scale ; 1 = bf16 ; 2 = fp32+bias ; 3 = bf16*scale
// bf16 paths use an LDS-staged coalesced store (full-line segments; the direct
// bf16 store's 32B segments caused ~2x HBM write amplification - r11 counters).

// ============ 256x256 4-PHASE GEMM-BT (proven; tail-drain fixed in r10) ============
template <int EPI>
__device__ __forceinline__ void gemm8p_body(
    const short* __restrict__ A, int lda,
    const short* __restrict__ B, int ldb,
    void* __restrict__ C, int ldc,
    const float* __restrict__ bias,
    int m0, int n0, int NK, float scale, short* lds) {

    const int tid = threadIdx.x;
    const int w = tid >> 6, lane = tid & 63;
    const int lo = lane & 15, g = lane >> 4;
    const int wr = w >> 2, wc = w & 3;

    const short* gA0 = A + (size_t)m0 * lda;
    const short* gA1 = A + (size_t)(m0 + 128) * lda;
    const short* gB0 = B + (size_t)n0 * ldb;
    const short* gB1 = B + (size_t)(n0 + 128) * ldb;

    f32x4 acc[8][4];
#pragma unroll
    for (int mf = 0; mf < 8; ++mf)
#pragma unroll
        for (int nf = 0; nf < 4; ++nf) acc[mf][nf] = (f32x4){0.f, 0.f, 0.f, 0.f};

    stage_half(gA0, lda, lds + 0,     tid);
    stage_half(gA1, lda, lds + 8192,  tid);
    stage_half(gB0, ldb, lds + 16384, tid);
    stage_half(gB1, ldb, lds + 24576, tid);
    stage_half(gB0 + BK, ldb, lds + 32768 + 16384, tid);
    stage_half(gB1 + BK, ldb, lds + 32768 + 24576, tid);
    asm volatile("s_waitcnt vmcnt(4)" ::: "memory");
    asm volatile("s_barrier" ::: "memory");

    for (int kt = 0; kt < NK; ++kt) {
        const int cb = (kt & 1) << 15;
        const int ob = cb ^ 32768;
        const int aBase = cb + wr * 8192;
        const int bBase = cb + 16384 + (wc >> 1) * 8192;
        const int brow  = (wc & 1) * 64;
        const int kA = (kt + 1) * BK, kB = (kt + 2) * BK;
        const bool doA = (kt + 1) < NK, doB = (kt + 2) < NK;

        bf16x8 bfr[4][2];
#pragma unroll
        for (int nf = 0; nf < 4; ++nf) {
            bfr[nf][0] = rdfrag(lds, bBase, brow + nf * 16 + lo, g);
            bfr[nf][1] = rdfrag(lds, bBase, brow + nf * 16 + lo, 4 + g);
        }
        PHASE(0, if (doA) stage_half(gA0 + kA, lda, lds + ob, tid), )
        PHASE(2, if (doA) stage_half(gA1 + kA, lda, lds + ob + 8192, tid), )
        PHASE(4, if (doB) stage_half(gB0 + kB, ldb, lds + cb + 16384, tid), )
        PHASE(6, if (doB) stage_half(gB1 + kB, ldb, lds + cb + 24576, tid),
                 {
                     if (doB) { asm volatile("s_waitcnt vmcnt(4)" ::: "memory"); }
                     else     { asm volatile("s_waitcnt vmcnt(0)" ::: "memory"); }
                 })
    }

    if constexpr (EPI == 0 || EPI == 2) {
#pragma unroll
        for (int nf = 0; nf < 4; ++nf) {
            const int col = n0 + wc * 64 + nf * 16 + lo;
            float bv = 0.f;
            if constexpr (EPI == 2) bv = bias[col];
#pragma unroll
            for (int mf = 0; mf < 8; ++mf) {
#pragma unroll
                for (int rr = 0; rr < 4; ++rr) {
                    const size_t oa =
                        (size_t)(m0 + wr * 128 + mf * 16 + g * 4 + rr) * ldc + col;
                    if constexpr (EPI == 0) ((float*)C)[oa] = acc[mf][nf][rr] * scale;
                    else                    ((float*)C)[oa] = acc[mf][nf][rr] + bv;
                }
            }
        }
    } else {
        // bf16: LDS-coalesced, two half-passes over m (rows 0-127 = wr0, 128-255 = wr1)
        const float sc_ = (EPI == 3) ? scale : 1.f;
#pragma unroll
        for (int half = 0; half < 2; ++half) {
            if (wr == half) {
#pragma unroll
                for (int nf = 0; nf < 4; ++nf)
#pragma unroll
                    for (int mf = 0; mf < 8; ++mf)
#pragma unroll
                        for (int rr = 0; rr < 4; ++rr)
                            lds[(mf * 16 + g * 4 + rr) * 264 + wc * 64 + nf * 16 + lo] =
                                f2bf(acc[mf][nf][rr] * sc_);
            }
            __syncthreads();
#pragma unroll
            for (int it = 0; it < 8; ++it) {
                const int idx = it * 512 + tid;
                const int r_  = idx >> 5;
                const int c_  = (idx & 31) * 8;
                *(bf16x8*)((short*)C + (size_t)(m0 + half * 128 + r_) * ldc + n0 + c_) =
                    *(const bf16x8*)&lds[r_ * 264 + c_];
            }
            __syncthreads();
        }
    }
}

// ============ 256x128 2-PHASE variant, tail-drain fixed (r10) ============
template <int EPI>
__device__ __forceinline__ void gemm8p_n128(
    const short* __restrict__ A, int lda,
    const short* __restrict__ B, int ldb,
    void* __restrict__ C, int ldc,
    const float* __restrict__ bias,
    int m0, int n0, int NK, float scale, short* lds) {

    const int tid = threadIdx.x;
    const int w = tid >> 6, lane = tid & 63;
    const int lo = lane & 15, g = lane >> 4;
    const int wr = w >> 1, wc = w & 1;

    const short* gA0 = A + (size_t)m0 * lda;
    const short* gA1 = A + (size_t)(m0 + 128) * lda;
    const short* gB0 = B + (size_t)n0 * ldb;

    f32x4 acc[4][4];
#pragma unroll
    for (int mf = 0; mf < 4; ++mf)
#pragma unroll
        for (int nf = 0; nf < 4; ++nf) acc[mf][nf] = (f32x4){0.f, 0.f, 0.f, 0.f};

    stage_half(gA0, lda, lds + 0,    tid);
    stage_half(gA1, lda, lds + 8192, tid);
    stage_half(gB0, ldb, lds + 16384, tid);
    stage_half(gB0 + BK, ldb, lds + 24576 + 16384, tid);
    asm volatile("s_waitcnt vmcnt(2)" ::: "memory");
    asm volatile("s_barrier" ::: "memory");

    for (int kt = 0; kt < NK; ++kt) {
        const int cbuf = (kt & 1) * 24576;
        const int obuf = cbuf ^ 24576;
        const int aBase = cbuf + (wr >> 1) * 8192 + (wr & 1) * 4096;
        const int bBase = cbuf + 16384 + wc * 4096;
        const int kA = (kt + 1) * BK, kB = (kt + 2) * BK;
        const bool doA = (kt + 1) < NK, doB = (kt + 2) < NK;

        bf16x8 bfr[4][2];
#pragma unroll
        for (int nf = 0; nf < 4; ++nf) {
            bfr[nf][0] = rdfrag(lds, bBase, nf * 16 + lo, g);
            bfr[nf][1] = rdfrag(lds, bBase, nf * 16 + lo, 4 + g);
        }
        PHASE(0, {
            if (doA) {
                stage_half(gA0 + kA, lda, lds + obuf, tid);
                stage_half(gA1 + kA, lda, lds + obuf + 8192, tid);
            }
        }, )
        PHASE(2, {
            if (doB) stage_half(gB0 + kB, ldb, lds + cbuf + 16384, tid);
        }, {
            if (doB) { asm volatile("s_waitcnt vmcnt(2)" ::: "memory"); }
            else     { asm volatile("s_waitcnt vmcnt(0)" ::: "memory"); }
        })
    }

    if constexpr (EPI == 0 || EPI == 2) {
#pragma unroll
        for (int nf = 0; nf < 4; ++nf) {
            const int col = n0 + wc * 64 + nf * 16 + lo;
            float bv = 0.f;
            if constexpr (EPI == 2) bv = bias[col];
#pragma unroll
            for (int mf = 0; mf < 4; ++mf) {
#pragma unroll
                for (int rr = 0; rr < 4; ++rr) {
                    const size_t oa =
                        (size_t)(m0 + wr * 64 + mf * 16 + g * 4 + rr) * ldc + col;
                    if constexpr (EPI == 0) ((float*)C)[oa] = acc[mf][nf][rr] * scale;
                    else                    ((float*)C)[oa] = acc[mf][nf][rr] + bv;
                }
            }
        }
    } else {
        // bf16: LDS-coalesced single pass, tile 256x128 in [256][136] shorts
        const float sc_ = (EPI == 3) ? scale : 1.f;
#pragma unroll
        for (int nf = 0; nf < 4; ++nf)
#pragma unroll
            for (int mf = 0; mf < 4; ++mf)
#pragma unroll
                for (int rr = 0; rr < 4; ++rr)
                    lds[(wr * 64 + mf * 16 + g * 4 + rr) * 136 + wc * 64 + nf * 16 + lo] =
                        f2bf(acc[mf][nf][rr] * sc_);
        __syncthreads();
#pragma unroll
        for (int it = 0; it < 8; ++it) {
            const int idx = it * 512 + tid;
            const int r_  = idx >> 4;
            const int c_  = (idx & 15) * 8;
            *(bf16x8*)((short*)C + (size_t)(m0 + r_) * ldc + n0 + c_) =
                *(const bf16x8*)&lds[r_ * 136 + c_];
        }
    }
}

// ---- gemm1: S[q][k] = bf16(scale * Qb·Kb^T) ; 256x256 tiles, grid nb*64 ----
__global__ __launch_bounds__(512, 2) void gemm1_kernel(
    const short* __restrict__ Qb, const short* __restrict__ Kb,
    short* __restrict__ Sb) {
    __shared__ __align__(16) short lds[65536];
    const int bid = xcd_swz(blockIdx.x, gridDim.x);
    const int cb = bid >> 6;
    const int t  = bid & 63;
    gemm8p_body<3>(Qb + (size_t)cb * LQS * DDIM, DDIM,
                   Kb + (size_t)cb * LKS * DDIM, DDIM,
                   Sb + (size_t)cb * ((size_t)LQS * LKS), LKS, nullptr,
                   (t >> 4) * 256, (t & 15) * 256, DDIM / BK, QKSCALE, lds);
}

// ---- gemm2: attedT[d][q] = VT·P^T ; 256x128 tiles, grid nb*32 (full chip) ----
__global__ __launch_bounds__(512, 2) void gemm2_kernel(
    const short* __restrict__ VT, const short* __restrict__ Pd,
    short* __restrict__ attedT) {
    __shared__ __align__(16) short lds[49152];
    const int bid = xcd_swz(blockIdx.x, gridDim.x);
    const int cb = bid >> 5;
    const int t  = bid & 31;
    gemm8p_n128<1>(VT + (size_t)cb * ((size_t)DDIM * LKS), LKS,
                   Pd + (size_t)cb * ((size_t)LQS * LKS), LKS,
                   attedT + (size_t)cb * ((size_t)DDIM * LQS), LQS, nullptr,
                   (t >> 3) * 256, (t & 7) * 128, LKS / BK, 1.f, lds);
}

// ---- merge: out[(b,d)][o] = attedT·Wb^T + bias ; 256x128, grid nb*32 ----
__global__ __launch_bounds__(512, 2) void merge_kernel(
    const short* __restrict__ attedT, const short* __restrict__ Wb,
    const float* __restrict__ bias, float* __restrict__ out) {
    __shared__ __align__(16) short lds[49152];
    const int bid = xcd_swz(blockIdx.x, gridDim.x);
    const int mt = bid >> 3;
    const int nt = bid & 7;
    gemm8p_n128<2>(attedT, DDIM, Wb, DDIM, out, DDIM, bias,
                   mt * 256, nt * 128, DDIM / BK, 1.f, lds);
}

// ---- softmax: one block per q-row; reads bf16 S, writes DENSE P bf16 ----
__global__ __launch_bounds__(256) void softmax_kernel(
    const short* __restrict__ Sb, short* __restrict__ Pd,
    const void* __restrict__ mask, const int* __restrict__ flags, int c0) {
    __shared__ float red[4];
    const int tid = threadIdx.x, w = tid >> 6, lane = tid & 63;
    const int cb = blockIdx.x >> 10;
    const int q  = blockIdx.x & 1023;
    const int mflag = flags[0];

    const short* Srow = Sb + ((size_t)cb * LQS + q) * LKS;
    const size_t roff = ((size_t)(c0 + cb) * LQS + q) * LKS;
    const size_t m4   = roff >> 2;   // int4 / uchar4 base index

    float sc[16];
#pragma unroll
    for (int j = 0; j < 2; ++j) {
        const int i8 = j * 256 + tid;
        const bf16x8 sv = ((const bf16x8*)Srow)[i8];
        int mm[8];
        if (mflag) {
            const int4 a = ((const int4*)mask)[m4 + 2 * i8];
            const int4 b = ((const int4*)mask)[m4 + 2 * i8 + 1];
            mm[0] = a.x; mm[1] = a.y; mm[2] = a.z; mm[3] = a.w;
            mm[4] = b.x; mm[5] = b.y; mm[6] = b.z; mm[7] = b.w;
        } else {
            const uchar4 a = ((const uchar4*)mask)[m4 + 2 * i8];
            const uchar4 b = ((const uchar4*)mask)[m4 + 2 * i8 + 1];
            mm[0] = a.x; mm[1] = a.y; mm[2] = a.z; mm[3] = a.w;
            mm[4] = b.x; mm[5] = b.y; mm[6] = b.z; mm[7] = b.w;
        }
#pragma unroll
        for (int i = 0; i < 8; ++i)
            sc[j * 8 + i] = mm[i] ? NEGINF : bf2f(sv[i]);
    }

    float lm = -INFINITY;
#pragma unroll
    for (int i = 0; i < 16; ++i) lm = fmaxf(lm, sc[i]);
#pragma unroll
    for (int off = 1; off < 64; off <<= 1) lm = fmaxf(lm, __shfl_xor(lm, off));
    if (lane == 0) red[w] = lm;
    __syncthreads();
    const float m = fmaxf(fmaxf(red[0], red[1]), fmaxf(red[2], red[3]));

    float p[16], ls = 0.f;
#pragma unroll
    for (int i = 0; i < 16; ++i) { p[i] = __expf(sc[i] - m); ls += p[i]; }
#pragma unroll
    for (int off = 1; off < 64; off <<= 1) ls += __shfl_xor(ls, off);
    __syncthreads();
    if (lane == 0) red[w] = ls;
    __syncthreads();
    const float inv = 1.f / (red[0] + red[1] + red[2] + red[3]);

    short* Prow = Pd + ((size_t)cb * LQS + q) * LKS;
#pragma unroll
    for (int j = 0; j < 2; ++j) {
        bf16x8 pv;
#pragma unroll
        for (int i = 0; i < 8; ++i) pv[i] = f2bf(p[j * 8 + i] * inv);
        ((bf16x8*)Prow)[j * 256 + tid] = pv;
    }
}

extern "C" void kernel_launch(void* const* d_in, const int* in_sizes, int n_in,
                              void* d_out, int out_size, void* d_ws, size_t ws_size,
                              hipStream_t stream) {
    // setup_inputs order: v, k, q, mask, W_merge, b_merge (fp32; mask i32/u8)
    const float* v    = (const float*)d_in[0];
    const float* k    = (const float*)d_in[1];
    const float* q    = (const float*)d_in[2];
    const void*  mask = d_in[3];
    const float* Wm   = (const float*)d_in[4];
    const float* bias = (const float*)d_in[5];
    float* out = (float*)d_out;

    // layout: flags 4KiB | Wb 2MiB | chunk arena nb*36MiB
    //   chunk: S region nb*16MiB (bf16 S uses first nb*8MiB) | VT nb*8MiB |
    //          attedT nb*2MiB | Qb nb*2MiB | Kb nb*8MiB
    // Pd (dense bf16 P, nb*8MiB) reuses Kb (dead after gemm1).
    const size_t base = 4096 + (2ull << 20);
    int nb = 0;
    for (int cand = 8; cand >= 1; cand >>= 1)
        if (base + (size_t)cand * (36ull << 20) <= ws_size) { nb = cand; break; }
    if (!nb) return;

    int*   flags = (int*)d_ws;
    short* Wb    = (short*)((char*)d_ws + 4096);
    char*  ar    = (char*)d_ws + base;
    short* Sb     = (short*)ar;
    short* VTbuf  = (short*)(ar + ((size_t)nb << 24));
    short* attedT = (short*)(ar + ((size_t)nb << 24) + ((size_t)nb << 23));
    short* Qb     = (short*)(ar + ((size_t)nb << 24) + ((size_t)nb << 23) + ((size_t)nb << 21));
    short* Kb     = (short*)(ar + ((size_t)nb << 24) + ((size_t)nb << 23) + 2 * ((size_t)nb << 21));
    short* Pd     = Kb;     // aliased: Kb dead after gemm1, Pd live softmax->gemm2

    hipLaunchKernelGGL(detect_kernel, dim3(1), dim3(64), 0, stream,
                       (const unsigned char*)mask, flags);
    hipLaunchKernelGGL(cvt_kernel, dim3(512), dim3(256), 0, stream,
                       Wm, Wb, (int)(DDIM * DDIM / 8));

    for (int c0 = 0; c0 < NBATCH; c0 += nb) {
        const float* vc = v + (size_t)c0 * LKS * DDIM;
        const float* kc = k + (size_t)c0 * LKS * DDIM;
        const float* qc = q + (size_t)c0 * LQS * DDIM;
        float*       oc = out + (size_t)c0 * DDIM * LQS;

        hipLaunchKernelGGL(cvt_kernel, dim3(1024), dim3(256), 0, stream,
                           qc, Qb, nb * (LQS * DDIM / 8));
        hipLaunchKernelGGL(cvt_kernel, dim3(2048), dim3(256), 0, stream,
                           kc, Kb, nb * (LKS * DDIM / 8));
        hipLaunchKernelGGL(transv_kernel, dim3(nb * 1024), dim3(256), 0, stream,
                           vc, VTbuf);
        hipLaunchKernelGGL(gemm1_kernel, dim3(nb * 64), dim3(512), 0, stream,
                           Qb, Kb, Sb);
        hipLaunchKernelGGL(softmax_kernel, dim3(nb * 1024), dim3(256), 0, stream,
                           Sb, Pd, mask, flags, c0);
        hipLaunchKernelGGL(gemm2_kernel, dim3(nb * 32), dim3(512), 0, stream,
                           VTbuf, Pd, attedT);
        hipLaunchKernelGGL(merge_kernel, dim3(nb * 32), dim3(512), 0, stream,
                           attedT, Wb, bias, oc);
    }
}